// Round 3
// baseline (703.180 us; speedup 1.0000x reference)
//
#include <hip/hip_runtime.h>
#include <math.h>

// B=4, TU=2048, TM=256, D=1024, H=16, DH=64, PAIRS=512
typedef unsigned short u16;
typedef __attribute__((ext_vector_type(8))) short bf16x8;
typedef __attribute__((ext_vector_type(4))) float f32x4;

__device__ __forceinline__ float sigmoidf_(float x) { return 1.0f / (1.0f + __expf(-x)); }
__device__ __forceinline__ u16 f2bf(float v) {
    union { float f; unsigned u; } x; x.f = v;
    unsigned r = x.u + 0x7fffu + ((x.u >> 16) & 1u);
    return (u16)(r >> 16);
}
__device__ __forceinline__ float bf2f(u16 u) {
    union { unsigned u; float f; } x; x.u = ((unsigned)u) << 16; return x.f;
}

// ---------------------------------------------------------------------------
// balance_norm + gate
// ---------------------------------------------------------------------------
__global__ void __launch_bounds__(256) norm_gate_kernel(
    const float* __restrict__ X,
    const float* __restrict__ w, const float* __restrict__ bvec,
    const float* __restrict__ bw_p,
    const float* __restrict__ gw, const float* __restrict__ gb_p,
    u16* __restrict__ OUT, float* __restrict__ G)
{
    const int row = blockIdx.x;
    const int t = threadIdx.x;
    const float* xr = X + (size_t)row * 1024;
    float4 x4 = *(const float4*)(xr + 4 * t);
    __shared__ float sh1[256], sh2[256];
    sh1[t] = x4.x + x4.y + x4.z + x4.w;
    sh2[t] = x4.x * x4.x + x4.y * x4.y + x4.z * x4.z + x4.w * x4.w;
    __syncthreads();
    for (int o = 64; o > 0; o >>= 1) {
        if ((t & 127) < o) sh2[t] += sh2[t + o];
        __syncthreads();
    }
    const float slo = sh2[0], shi = sh2[128];
    for (int o = 128; o > 0; o >>= 1) {
        if (t < o) sh1[t] += sh1[t + o];
        __syncthreads();
    }
    const float mu = sh1[0] * (1.0f / 1024.0f);
    const float var = (slo + shi) * (1.0f / 1024.0f) - mu * mu;
    const float rstd = rsqrtf(var + 1e-6f);
    const float imb = (slo - shi) * (1.0f / 512.0f) * (*bw_p);
    const float corr = (t < 128) ? -imb : imb;
    const int i0 = 4 * t;
    float o0 = (x4.x - mu) * rstd * w[i0 + 0] + bvec[i0 + 0] + corr;
    float o1 = (x4.y - mu) * rstd * w[i0 + 1] + bvec[i0 + 1] + corr;
    float o2 = (x4.z - mu) * rstd * w[i0 + 2] + bvec[i0 + 2] + corr;
    float o3 = (x4.w - mu) * rstd * w[i0 + 3] + bvec[i0 + 3] + corr;
    float gd = o0 * gw[i0 + 0] + o1 * gw[i0 + 1] + o2 * gw[i0 + 2] + o3 * gw[i0 + 3];
    __syncthreads();
    sh1[t] = gd;
    __syncthreads();
    for (int o = 128; o > 0; o >>= 1) {
        if (t < o) sh1[t] += sh1[t + o];
        __syncthreads();
    }
    if (t == 0) G[row] = sigmoidf_(sh1[0] + *gb_p);
    u16 ob[4] = { f2bf(o0), f2bf(o1), f2bf(o2), f2bf(o3) };
    *(uint2*)(OUT + (size_t)row * 1024 + i0) = *(uint2*)ob;
}

// ---------------------------------------------------------------------------
// weight fp32 -> bf16 (8 slots of 1M elements)
// ---------------------------------------------------------------------------
__global__ void __launch_bounds__(256) wconv_kernel(
    const float* w0, const float* w1, const float* w2, const float* w3,
    const float* w4, const float* w5, const float* w6, const float* w7,
    u16* __restrict__ dst)
{
    const float* s;
    switch (blockIdx.y) {
        case 0: s = w0; break; case 1: s = w1; break;
        case 2: s = w2; break; case 3: s = w3; break;
        case 4: s = w4; break; case 5: s = w5; break;
        case 6: s = w6; break; default: s = w7; break;
    }
    long i = (long)blockIdx.x * 1024 + threadIdx.x * 4;
    float4 v = *(const float4*)(s + i);
    u16 o[4] = { f2bf(v.x), f2bf(v.y), f2bf(v.z), f2bf(v.w) };
    *(uint2*)(dst + (long)blockIdx.y * 1048576 + i) = *(uint2*)o;
}

__global__ void __launch_bounds__(256) cvt_kernel(const float* __restrict__ S, u16* __restrict__ D)
{
    long i = ((long)blockIdx.x * 256 + threadIdx.x) * 4;
    float4 v = *(const float4*)(S + i);
    u16 o[4] = { f2bf(v.x), f2bf(v.y), f2bf(v.z), f2bf(v.w) };
    *(uint2*)(D + i) = *(uint2*)o;
}

// ---------------------------------------------------------------------------
// pair (phase) normalization on bf16
// ---------------------------------------------------------------------------
__global__ void __launch_bounds__(256) pairnorm_kernel(
    const u16* __restrict__ X, u16* __restrict__ Y, int n8)
{
    int i = blockIdx.x * 256 + threadIdx.x;
    if (i >= n8) return;
    uint4 v = *(const uint4*)(X + (long)i * 8);
    u16 in[8]; *(uint4*)in = v;
    u16 o[8];
    #pragma unroll
    for (int j = 0; j < 4; ++j) {
        float x = bf2f(in[2 * j]) + 1e-8f, y = bf2f(in[2 * j + 1]) + 1e-8f;
        float r = rsqrtf(x * x + y * y);
        o[2 * j] = f2bf(x * r); o[2 * j + 1] = f2bf(y * r);
    }
    *(uint4*)(Y + (long)i * 8) = *(uint4*)o;
}

// ---------------------------------------------------------------------------
// bf16 NT MFMA GEMM, 128xBN tile, BK=32, 256 threads (2x2 waves).
// LDS in MFMA-FRAGMENT order: subtile s (16 rows x 32 cols) stored as
// [64 lanes][8 u16] in the exact order ds_read_b128 consumes it ->
// conflict-free LDS reads, linear global_load_lds dest, per-lane swizzled
// global source (m173 pattern).
// Bijective XCD swizzle on full linear block id (m204).
// EPI 0: bf16 store    1: f32 store    2: f32 atomicAdd
//     3: f32 base[idx]+acc*rs[m]       4: bf16 head-transposed store
//     5: resonance blend C=.7*base+.3*v ; OT[n*ldt+m]=.7*accB+.3*v
// ---------------------------------------------------------------------------
template<int BN, int EPI>
__global__ void __launch_bounds__(256) mfma_nt(
    const u16* __restrict__ A, long zA,
    const u16* __restrict__ B, long zB,
    void* __restrict__ C, long zC,
    int K, int lda, int ldb, int ldc, float alpha, int nsplit,
    const float* __restrict__ base, const float* __restrict__ rs,
    const float* __restrict__ accB, float* __restrict__ OT,
    long zOT, int ldt, int l2T, long bstr)
{
    constexpr int NR = BN / 32;
    __shared__ __align__(16) u16 As[128 * 32];
    __shared__ __align__(16) u16 Bs[BN * 32];
    // --- bijective XCD swizzle over the whole grid ---
    const int gx = gridDim.x, gy = gridDim.y;
    const int nwg = gx * gy * gridDim.z;
    const int lin = blockIdx.x + gx * (blockIdx.y + gy * blockIdx.z);
    const int q8 = nwg >> 3, r8 = nwg & 7;
    const int xcd = lin & 7, off = lin >> 3;
    const int swz = (xcd < r8 ? xcd * (q8 + 1) : r8 * (q8 + 1) + (xcd - r8) * q8) + off;
    const int bx = swz % gx;
    const int tmp = swz / gx;
    const int by = tmp % gy;
    const int bz = tmp / gy;

    const int t = threadIdx.x;
    const int lane = t & 63, w = t >> 6;
    const int wr = w >> 1, wc = w & 1;
    const int slab = bz / nsplit, ks = bz - slab * nsplit;
    const int kchunk = K / nsplit;
    int k0 = ks * kchunk;
    const int kend = k0 + kchunk;
    const long m0 = (long)by * 128;
    const long n0 = (long)bx * BN;
    const int frow = lane & 15, fko = (lane >> 4) * 8;
    // per-lane fragment-order global sources
    const u16* gaA = A + zA * slab + (m0 + 32 * w + frow) * lda + fko;   // subtiles 2w,2w+1
    const u16* gbB;
    if constexpr (BN == 128) gbB = B + zB * slab + (n0 + 32 * w + frow) * ldb + fko;
    else                     gbB = B + zB * slab + (n0 + 16 * w + frow) * ldb + fko;
    f32x4 acc[4][NR] = {};
    for (; k0 < kend; k0 += 32) {
        __builtin_amdgcn_global_load_lds((const __attribute__((address_space(1))) void*)(gaA + k0),
            (__attribute__((address_space(3))) void*)(As + 2 * w * 512), 16, 0, 0);
        __builtin_amdgcn_global_load_lds((const __attribute__((address_space(1))) void*)(gaA + 16L * lda + k0),
            (__attribute__((address_space(3))) void*)(As + (2 * w + 1) * 512), 16, 0, 0);
        if constexpr (BN == 128) {
            __builtin_amdgcn_global_load_lds((const __attribute__((address_space(1))) void*)(gbB + k0),
                (__attribute__((address_space(3))) void*)(Bs + 2 * w * 512), 16, 0, 0);
            __builtin_amdgcn_global_load_lds((const __attribute__((address_space(1))) void*)(gbB + 16L * ldb + k0),
                (__attribute__((address_space(3))) void*)(Bs + (2 * w + 1) * 512), 16, 0, 0);
        } else {
            __builtin_amdgcn_global_load_lds((const __attribute__((address_space(1))) void*)(gbB + k0),
                (__attribute__((address_space(3))) void*)(Bs + w * 512), 16, 0, 0);
        }
        __syncthreads();
        bf16x8 af[4], bfr[NR];
        #pragma unroll
        for (int m = 0; m < 4; ++m)
            af[m] = *(const bf16x8*)(As + (wr * 4 + m) * 512 + lane * 8);
        #pragma unroll
        for (int n = 0; n < NR; ++n)
            bfr[n] = *(const bf16x8*)(Bs + (wc * NR + n) * 512 + lane * 8);
        #pragma unroll
        for (int m = 0; m < 4; ++m)
            #pragma unroll
            for (int n = 0; n < NR; ++n)
                acc[m][n] = __builtin_amdgcn_mfma_f32_16x16x32_bf16(af[m], bfr[n], acc[m][n], 0, 0, 0);
        __syncthreads();
    }
    const int l15 = lane & 15, l4 = lane >> 4;
    #pragma unroll
    for (int m = 0; m < 4; ++m) {
        #pragma unroll
        for (int n = 0; n < NR; ++n) {
            #pragma unroll
            for (int j = 0; j < 4; ++j) {
                const long grow = m0 + wr * 64 + m * 16 + l4 * 4 + j;
                const long gcol = n0 + wc * (BN / 2) + n * 16 + l15;
                const float v = acc[m][n][j] * alpha;
                if constexpr (EPI == 0) {
                    ((u16*)C)[zC * slab + grow * ldc + gcol] = f2bf(v);
                } else if constexpr (EPI == 1) {
                    ((float*)C)[zC * slab + grow * ldc + gcol] = v;
                } else if constexpr (EPI == 2) {
                    atomicAdd((float*)C + zC * slab + grow * ldc + gcol, v);
                } else if constexpr (EPI == 3) {
                    const long idx = grow * ldc + gcol;
                    ((float*)C)[idx] = base[idx] + v * rs[grow];
                } else if constexpr (EPI == 4) {
                    const long bb = grow >> l2T;
                    const long tt = grow & (ldt - 1);
                    ((u16*)C)[bb * bstr + gcol * (long)ldt + tt] = f2bf(v);
                } else {
                    const long idx = zC * slab + grow * ldc + gcol;
                    ((float*)C)[idx] = 0.7f * base[idx] + 0.3f * v;
                    const long tidx = zOT * slab + gcol * (long)ldt + grow;
                    OT[tidx] = 0.7f * accB[tidx] + 0.3f * v;
                }
            }
        }
    }
}

// ---------------------------------------------------------------------------
// softmax + gate + renorm, IN PLACE on bf16 scores; one wave per row.
// NU2 = row_len/128 (bf16-pair vectorized).
// w[q,k] = e_k*eg_k*ag / (ag*sum(e*eg) + l*1e-8)
// ---------------------------------------------------------------------------
template<int NU2>
__global__ void __launch_bounds__(256) softmax_gate_kernel(
    u16* __restrict__ P,
    const float* __restrict__ AG, const float* __restrict__ EG, int qmask)
{
    const int row = blockIdx.x * 4 + (threadIdx.x >> 6);
    const int lane = threadIdx.x & 63;
    const int q = row & qmask;
    unsigned* pr = (unsigned*)(P + (long)row * (NU2 * 128));
    float r0[NU2], r1[NU2];
    float m = -3.4e38f;
    #pragma unroll
    for (int u = 0; u < NU2; ++u) {
        unsigned v = pr[lane + 64 * u];
        r0[u] = bf2f((u16)(v & 0xffffu));
        r1[u] = bf2f((u16)(v >> 16));
        m = fmaxf(m, fmaxf(r0[u], r1[u]));
    }
    for (int o = 32; o > 0; o >>= 1) m = fmaxf(m, __shfl_xor(m, o));
    float l = 0.0f, se = 0.0f;
    #pragma unroll
    for (int u = 0; u < NU2; ++u) {
        float e0 = __expf(r0[u] - m), e1 = __expf(r1[u] - m);
        l += e0 + e1;
        float2 eg = *(const float2*)(EG + 2 * (lane + 64 * u));
        r0[u] = e0 * eg.x; r1[u] = e1 * eg.y;
        se += r0[u] + r1[u];
    }
    for (int o = 32; o > 0; o >>= 1) { l += __shfl_xor(l, o); se += __shfl_xor(se, o); }
    const float ag = AG[q];
    const float f = ag / (ag * se + l * 1e-8f);
    #pragma unroll
    for (int u = 0; u < NU2; ++u) {
        unsigned vo = (unsigned)f2bf(r0[u] * f) | ((unsigned)f2bf(r1[u] * f) << 16);
        pr[lane + 64 * u] = vo;
    }
}

__global__ void __launch_bounds__(256) rowmean_sig_kernel(
    const float* __restrict__ X, int len, float invlen,
    const float* __restrict__ alpha_p, float* __restrict__ OUT)
{
    const int row = blockIdx.x * 4 + (threadIdx.x >> 6);
    const int lane = threadIdx.x & 63;
    const float* xr = X + (long)row * len;
    float s = 0.0f;
    for (int k = lane; k < len; k += 64) s += xr[k];
    for (int o = 32; o > 0; o >>= 1) s += __shfl_xor(s, o);
    if (lane == 0) OUT[row] = sigmoidf_((*alpha_p) * s * invlen);
}

#define MFMA_TAIL nullptr, nullptr, nullptr, nullptr, 0L, 0, 0, 0L

extern "C" void kernel_launch(void* const* d_in, const int* in_sizes, int n_in,
                              void* d_out, int out_size, void* d_ws, size_t ws_size,
                              hipStream_t stream)
{
    (void)in_sizes; (void)n_in; (void)out_size; (void)ws_size;
    const float* o_micro    = (const float*)d_in[0];
    const float* o_macro    = (const float*)d_in[1];
    const float* r_conv_acc = (const float*)d_in[2];
    const float* r_emer_acc = (const float*)d_in[3];
    const float* ln_u_w = (const float*)d_in[4];
    const float* ln_u_b = (const float*)d_in[5];
    const float* bw_u   = (const float*)d_in[6];
    const float* ln_m_w = (const float*)d_in[7];
    const float* ln_m_b = (const float*)d_in[8];
    const float* bw_m   = (const float*)d_in[9];
    const float* gu_w   = (const float*)d_in[10];
    const float* gu_b   = (const float*)d_in[11];
    const float* gm_w   = (const float*)d_in[12];
    const float* gm_b   = (const float*)d_in[13];
    const float* wq_c   = (const float*)d_in[14];
    const float* wk_c   = (const float*)d_in[15];
    const float* wv_c   = (const float*)d_in[16];
    const float* wo_c   = (const float*)d_in[17];
    const float* wq_e   = (const float*)d_in[18];
    const float* wk_e   = (const float*)d_in[19];
    const float* wv_e   = (const float*)d_in[20];
    const float* wo_e   = (const float*)d_in[21];
    const float* res_alpha = (const float*)d_in[22];

    float* out = (float*)d_out;
    float* out_micro = out;              // (4,2048,1024)
    float* out_macro = out + 8388608;    // (4,256,1024)
    float* out_rconv = out + 9437184;    // (4,256,2048)
    float* out_remer = out + 11534336;   // (4,2048,256)

    // workspace (f32 slot offsets; bf16 buffers use 2 el/slot)
    float* ws = (float*)d_ws;
    u16* OUb = (u16*)ws;                       // 8388608 bf16 (normed micro)
    u16* OMb = (u16*)(ws + 4194304);           // 1048576 bf16 (normed macro)
    u16* WB  = (u16*)(ws + 4718592);           // 8 x 1048576 bf16 weights
    u16* Kcb = (u16*)(ws + 8912896);           // conv K (8192x1024) -> later CTe
    u16* VTc = (u16*)(ws + 13107200);          // conv V^T [b][h][64][2048]
    u16* Qeb = (u16*)(ws + 17301504);          // emer Q (8192x1024)
    u16* Qcb = (u16*)(ws + 21495808);          // conv Q (1024x1024) -> later CTb
    u16* Keb = (u16*)(ws + 22020096);          // emer K (1024x1024)
    u16* VTe = (u16*)(ws + 22544384);          // emer V^T [b][h][64][256]
    u16* PNu = (u16*)(ws + 23068672);          // pairnormed micro (8.4M bf16)
    float* CT = ws + 27262976;                 // conv ctx f32 (4x256x1024); early: PNm
    float* GU = ws + 28311552;                 // 8192
    float* GM = GU + 8192;                     // 1024
    float* RCS = GM + 1024;                    // 1024
    float* RES = RCS + 1024;                   // 8192
    u16* PNm = (u16*)CT;
    u16* CTb = Qcb;
    u16* CTe = Kcb;
    u16* SCu = (u16*)out_micro;                // per-batch bf16 score/prob slab (8.4M)

    // 1. weights -> bf16
    wconv_kernel<<<dim3(1024, 8), 256, 0, stream>>>(wq_c, wk_c, wv_c, wo_c, wq_e, wk_e, wv_e, wo_e, WB);
    // 2. balance norms + gates
    norm_gate_kernel<<<8192, 256, 0, stream>>>(o_micro, ln_u_w, ln_u_b, bw_u, gu_w, gu_b, OUb, GU);
    norm_gate_kernel<<<1024, 256, 0, stream>>>(o_macro, ln_m_w, ln_m_b, bw_m, gm_w, gm_b, OMb, GM);
    // 3. pair-normalize for resonance
    pairnorm_kernel<<<4096, 256, 0, stream>>>(OUb, PNu, 1048576);
    pairnorm_kernel<<<512, 256, 0, stream>>>(OMb, PNm, 131072);
    // 4. resonance GEMM + 0.7/0.3 blend + transposed write
    mfma_nt<128, 5><<<dim3(16, 2, 4), 256, 0, stream>>>(
        PNm, 262144L, PNu, 2097152L, out_rconv, 524288L,
        1024, 1024, 1024, 2048, 1.0f / 512.0f, 1,
        r_conv_acc, nullptr, r_emer_acc, out_remer, 524288L, 256, 0, 0L);
    // 5. resonance scalars
    rowmean_sig_kernel<<<256, 256, 0, stream>>>(out_rconv, 2048, 1.0f / 2048.0f, res_alpha, RCS);
    rowmean_sig_kernel<<<2048, 256, 0, stream>>>(out_remer, 256, 1.0f / 256.0f, res_alpha, RES);
    // 6. projections (NT, weights (N,K) K-contiguous)
    mfma_nt<128, 0><<<dim3(8, 64, 1), 256, 0, stream>>>(OUb, 0L, WB + 1 * 1048576, 0L, Kcb, 0L,
        1024, 1024, 1024, 1024, 1.0f, 1, MFMA_TAIL);
    mfma_nt<128, 4><<<dim3(8, 64, 1), 256, 0, stream>>>(OUb, 0L, WB + 2 * 1048576, 0L, VTc, 0L,
        1024, 1024, 1024, 0, 1.0f, 1, nullptr, nullptr, nullptr, nullptr, 0L, 2048, 11, 2097152L);
    mfma_nt<128, 0><<<dim3(8, 64, 1), 256, 0, stream>>>(OUb, 0L, WB + 4 * 1048576, 0L, Qeb, 0L,
        1024, 1024, 1024, 1024, 1.0f, 1, MFMA_TAIL);
    mfma_nt<128, 0><<<dim3(8, 8, 1), 256, 0, stream>>>(OMb, 0L, WB + 0 * 1048576, 0L, Qcb, 0L,
        1024, 1024, 1024, 1024, 1.0f, 1, MFMA_TAIL);
    mfma_nt<128, 0><<<dim3(8, 8, 1), 256, 0, stream>>>(OMb, 0L, WB + 5 * 1048576, 0L, Keb, 0L,
        1024, 1024, 1024, 1024, 1.0f, 1, MFMA_TAIL);
    mfma_nt<128, 4><<<dim3(8, 8, 1), 256, 0, stream>>>(OMb, 0L, WB + 6 * 1048576, 0L, VTe, 0L,
        1024, 1024, 1024, 0, 1.0f, 1, nullptr, nullptr, nullptr, nullptr, 0L, 256, 8, 262144L);
    // 7. conv ctx accumulator
    (void)hipMemsetAsync(CT, 0, 1048576 * sizeof(float), stream);
    // 8. conv attention per batch (bf16 scores in place in SCu)
    for (int b = 0; b < 4; ++b) {
        mfma_nt<128, 0><<<dim3(16, 2, 16), 256, 0, stream>>>(
            Qcb + (long)b * 262144, 64L, Kcb + (long)b * 2097152, 64L, SCu, 524288L,
            64, 1024, 1024, 2048, 0.125f, 1, MFMA_TAIL);
        softmax_gate_kernel<16><<<1024, 256, 0, stream>>>(SCu, GM + b * 256, GU + b * 2048, 255);
        mfma_nt<64, 2><<<dim3(1, 2, 128), 256, 0, stream>>>(
            SCu, 524288L, VTc + (long)b * 2097152, 131072L, CT + (long)b * 262144, 64L,
            2048, 2048, 2048, 1024, 1.0f, 8, MFMA_TAIL);
    }
    // 9-10. conv out-proj + residual + r_conv_scalar -> o_macro_new
    cvt_kernel<<<1024, 256, 0, stream>>>(CT, CTb);
    mfma_nt<128, 3><<<dim3(8, 8, 1), 256, 0, stream>>>(CTb, 0L, WB + 3 * 1048576, 0L, out_macro, 0L,
        1024, 1024, 1024, 1024, 1.0f, 1, o_macro, RCS, nullptr, nullptr, 0L, 0, 0, 0L);
    // 11. emer attention per batch
    for (int b = 0; b < 4; ++b) {
        mfma_nt<128, 0><<<dim3(2, 16, 16), 256, 0, stream>>>(
            Qeb + (long)b * 2097152, 64L, Keb + (long)b * 262144, 64L, SCu, 524288L,
            64, 1024, 1024, 256, 0.125f, 1, MFMA_TAIL);
        softmax_gate_kernel<2><<<8192, 256, 0, stream>>>(SCu, GU + b * 2048, GM + b * 256, 2047);
        mfma_nt<64, 0><<<dim3(1, 16, 16), 256, 0, stream>>>(
            SCu, 524288L, VTe + (long)b * 262144, 16384L, (void*)(CTe + (long)b * 2097152), 64L,
            256, 256, 256, 1024, 1.0f, 1, MFMA_TAIL);
    }
    // 12. emer out-proj + residual + r_emer_scalar -> o_micro_new
    mfma_nt<128, 3><<<dim3(8, 64, 1), 256, 0, stream>>>(CTe, 0L, WB + 7 * 1048576, 0L, out_micro, 0L,
        1024, 1024, 1024, 1024, 1.0f, 1, o_micro, RES, nullptr, nullptr, 0L, 0, 0, 0L);
}

// Round 4
// 575.849 us; speedup vs baseline: 1.2211x; 1.2211x over previous
//
#include <hip/hip_runtime.h>
#include <math.h>

// B=4, TU=2048, TM=256, D=1024, H=16, DH=64, PAIRS=512
typedef unsigned short u16;
typedef __attribute__((ext_vector_type(8))) short bf16x8;
typedef __attribute__((ext_vector_type(4))) float f32x4;

__device__ __forceinline__ float sigmoidf_(float x) { return 1.0f / (1.0f + __expf(-x)); }
__device__ __forceinline__ u16 f2bf(float v) {
    union { float f; unsigned u; } x; x.f = v;
    unsigned r = x.u + 0x7fffu + ((x.u >> 16) & 1u);
    return (u16)(r >> 16);
}
__device__ __forceinline__ float bf2f(u16 u) {
    union { unsigned u; float f; } x; x.u = ((unsigned)u) << 16; return x.f;
}

// ---------------------------------------------------------------------------
// balance_norm + gate + fused pair(phase)-normalization.
// One block per row of 1024. Writes normed bf16 row, pairnormed bf16 row,
// and the sigmoid(row . gw + gb) gate scalar.
// ---------------------------------------------------------------------------
__global__ void __launch_bounds__(256) norm_gate_kernel(
    const float* __restrict__ X,
    const float* __restrict__ w, const float* __restrict__ bvec,
    const float* __restrict__ bw_p,
    const float* __restrict__ gw, const float* __restrict__ gb_p,
    u16* __restrict__ OUT, u16* __restrict__ PN, float* __restrict__ G)
{
    const int row = blockIdx.x;
    const int t = threadIdx.x;
    const float* xr = X + (size_t)row * 1024;
    float4 x4 = *(const float4*)(xr + 4 * t);
    __shared__ float sh1[256], sh2[256];
    sh1[t] = x4.x + x4.y + x4.z + x4.w;
    sh2[t] = x4.x * x4.x + x4.y * x4.y + x4.z * x4.z + x4.w * x4.w;
    __syncthreads();
    for (int o = 64; o > 0; o >>= 1) {
        if ((t & 127) < o) sh2[t] += sh2[t + o];
        __syncthreads();
    }
    const float slo = sh2[0], shi = sh2[128];
    for (int o = 128; o > 0; o >>= 1) {
        if (t < o) sh1[t] += sh1[t + o];
        __syncthreads();
    }
    const float mu = sh1[0] * (1.0f / 1024.0f);
    const float var = (slo + shi) * (1.0f / 1024.0f) - mu * mu;
    const float rstd = rsqrtf(var + 1e-6f);
    const float imb = (slo - shi) * (1.0f / 512.0f) * (*bw_p);
    const float corr = (t < 128) ? -imb : imb;
    const int i0 = 4 * t;
    float o0 = (x4.x - mu) * rstd * w[i0 + 0] + bvec[i0 + 0] + corr;
    float o1 = (x4.y - mu) * rstd * w[i0 + 1] + bvec[i0 + 1] + corr;
    float o2 = (x4.z - mu) * rstd * w[i0 + 2] + bvec[i0 + 2] + corr;
    float o3 = (x4.w - mu) * rstd * w[i0 + 3] + bvec[i0 + 3] + corr;
    float gd = o0 * gw[i0 + 0] + o1 * gw[i0 + 1] + o2 * gw[i0 + 2] + o3 * gw[i0 + 3];
    __syncthreads();
    sh1[t] = gd;
    __syncthreads();
    for (int o = 128; o > 0; o >>= 1) {
        if (t < o) sh1[t] += sh1[t + o];
        __syncthreads();
    }
    if (t == 0) G[row] = sigmoidf_(sh1[0] + *gb_p);
    u16 ob[4] = { f2bf(o0), f2bf(o1), f2bf(o2), f2bf(o3) };
    *(uint2*)(OUT + (size_t)row * 1024 + i0) = *(uint2*)ob;
    // fused pair-normalization (pairs are thread-local: i0 is even)
    float pa = o0 + 1e-8f, pb = o1 + 1e-8f;
    float r0 = rsqrtf(pa * pa + pb * pb);
    float pc = o2 + 1e-8f, pd = o3 + 1e-8f;
    float r1 = rsqrtf(pc * pc + pd * pd);
    u16 pn[4] = { f2bf(pa * r0), f2bf(pb * r0), f2bf(pc * r1), f2bf(pd * r1) };
    *(uint2*)(PN + (size_t)row * 1024 + i0) = *(uint2*)pn;
}

// ---------------------------------------------------------------------------
// weight fp32 -> bf16 (8 slots of 1M elements; order set by pointer args)
// ---------------------------------------------------------------------------
__global__ void __launch_bounds__(256) wconv_kernel(
    const float* w0, const float* w1, const float* w2, const float* w3,
    const float* w4, const float* w5, const float* w6, const float* w7,
    u16* __restrict__ dst)
{
    const float* s;
    switch (blockIdx.y) {
        case 0: s = w0; break; case 1: s = w1; break;
        case 2: s = w2; break; case 3: s = w3; break;
        case 4: s = w4; break; case 5: s = w5; break;
        case 6: s = w6; break; default: s = w7; break;
    }
    long i = (long)blockIdx.x * 1024 + threadIdx.x * 4;
    float4 v = *(const float4*)(s + i);
    u16 o[4] = { f2bf(v.x), f2bf(v.y), f2bf(v.z), f2bf(v.w) };
    *(uint2*)(dst + (long)blockIdx.y * 1048576 + i) = *(uint2*)o;
}

__global__ void __launch_bounds__(256) cvt_kernel(const float* __restrict__ S, u16* __restrict__ D)
{
    long i = ((long)blockIdx.x * 256 + threadIdx.x) * 4;
    float4 v = *(const float4*)(S + i);
    u16 o[4] = { f2bf(v.x), f2bf(v.y), f2bf(v.z), f2bf(v.w) };
    *(uint2*)(D + i) = *(uint2*)o;
}

// ---------------------------------------------------------------------------
// bf16 NT MFMA GEMM, 128xBN tile, BK=32, 256 threads (2x2 waves),
// DOUBLE-BUFFERED 2-phase K-loop: stage tile k+1 (global_load_lds) into the
// alternate LDS buffer BEFORE computing tile k; single __syncthreads()/iter
// (its implicit vmcnt(0)+lgkmcnt(0) drain is the fence).
// LDS is in MFMA-fragment order (m173 pattern): conflict-free ds_read_b128,
// linear LDS dest, per-lane swizzled global source.
// SWZ: bijective XCD swizzle (m204) — on for big HBM-bound GEMMs only.
// EPI 0: bf16 store                 2: f32 atomicAdd
//     3: f32 base[idx]+acc*rs[m]    5: resonance blend + transposed write
//     6: micro fused 3-way (Kc | VTc transposed | Qe)
//     7: macro fused 3-way (Qc | Ke | VTe transposed)
// ---------------------------------------------------------------------------
template<int BN, int EPI, bool SWZ>
__global__ void __launch_bounds__(256) mfma_nt(
    const u16* __restrict__ A, long zA,
    const u16* __restrict__ B, long zB,
    void* __restrict__ C, long zC,
    void* __restrict__ Cx, void* __restrict__ Cy,
    int K, int lda, int ldb, int ldc, float alpha, int nsplit,
    const float* __restrict__ base, const float* __restrict__ rs,
    const float* __restrict__ accB, float* __restrict__ OT,
    long zOT, int ldt)
{
    constexpr int NR = BN / 32;
    __shared__ __align__(16) u16 As[2][128 * 32];
    __shared__ __align__(16) u16 Bs[2][BN * 32];
    int bx, by, bz;
    if constexpr (SWZ) {
        const int gx = gridDim.x, gy = gridDim.y;
        const int nwg = gx * gy * gridDim.z;
        const int lin = blockIdx.x + gx * (blockIdx.y + gy * blockIdx.z);
        const int q8 = nwg >> 3, r8 = nwg & 7;
        const int xcd = lin & 7, off = lin >> 3;
        const int swz = (xcd < r8 ? xcd * (q8 + 1) : r8 * (q8 + 1) + (xcd - r8) * q8) + off;
        bx = swz % gx;
        const int tmp = swz / gx;
        by = tmp % gy;
        bz = tmp / gy;
    } else {
        bx = blockIdx.x; by = blockIdx.y; bz = blockIdx.z;
    }
    const int t = threadIdx.x;
    const int lane = t & 63, w = t >> 6;
    const int wr = w >> 1, wc = w & 1;
    const int slab = bz / nsplit, ks = bz - slab * nsplit;
    const int kchunk = K / nsplit;
    const int kbeg = ks * kchunk, kend = kbeg + kchunk;
    const long m0 = (long)by * 128;
    const long n0 = (long)bx * BN;
    const int frow = lane & 15, fko = (lane >> 4) * 8;
    const u16* gaA = A + zA * slab + (m0 + 32 * w + frow) * lda + fko;
    const u16* gbB;
    if constexpr (BN == 128) gbB = B + zB * slab + (n0 + 32 * w + frow) * ldb + fko;
    else                     gbB = B + zB * slab + (n0 + 16 * w + frow) * ldb + fko;

#define GLD(src, dst) __builtin_amdgcn_global_load_lds( \
        (const __attribute__((address_space(1))) void*)(src), \
        (__attribute__((address_space(3))) void*)(dst), 16, 0, 0)

    auto stage = [&](int kk, int p) {
        GLD(gaA + kk, &As[p][2 * w * 512]);
        GLD(gaA + 16L * lda + kk, &As[p][(2 * w + 1) * 512]);
        if constexpr (BN == 128) {
            GLD(gbB + kk, &Bs[p][2 * w * 512]);
            GLD(gbB + 16L * ldb + kk, &Bs[p][(2 * w + 1) * 512]);
        } else {
            GLD(gbB + kk, &Bs[p][w * 512]);
        }
    };

    f32x4 acc[4][NR] = {};
    stage(kbeg, 0);
    __syncthreads();
    int cur = 0;
    for (int k0 = kbeg; k0 < kend; k0 += 32) {
        if (k0 + 32 < kend) stage(k0 + 32, cur ^ 1);
        bf16x8 af[4], bfr[NR];
        #pragma unroll
        for (int m = 0; m < 4; ++m)
            af[m] = *(const bf16x8*)(&As[cur][(wr * 4 + m) * 512 + lane * 8]);
        #pragma unroll
        for (int n = 0; n < NR; ++n)
            bfr[n] = *(const bf16x8*)(&Bs[cur][(wc * NR + n) * 512 + lane * 8]);
        #pragma unroll
        for (int m = 0; m < 4; ++m)
            #pragma unroll
            for (int n = 0; n < NR; ++n)
                acc[m][n] = __builtin_amdgcn_mfma_f32_16x16x32_bf16(af[m], bfr[n], acc[m][n], 0, 0, 0);
        __syncthreads();
        cur ^= 1;
    }
#undef GLD
    const int l15 = lane & 15, l4 = lane >> 4;
    #pragma unroll
    for (int m = 0; m < 4; ++m) {
        #pragma unroll
        for (int n = 0; n < NR; ++n) {
            #pragma unroll
            for (int j = 0; j < 4; ++j) {
                const long grow = m0 + wr * 64 + m * 16 + l4 * 4 + j;
                const long gcol = n0 + wc * (BN / 2) + n * 16 + l15;
                const float v = acc[m][n][j] * alpha;
                if constexpr (EPI == 0) {
                    ((u16*)C)[zC * slab + grow * ldc + gcol] = f2bf(v);
                } else if constexpr (EPI == 2) {
                    atomicAdd((float*)C + zC * slab + grow * ldc + gcol, v);
                } else if constexpr (EPI == 3) {
                    const long idx = grow * ldc + gcol;
                    ((float*)C)[idx] = base[idx] + v * rs[grow];
                } else if constexpr (EPI == 5) {
                    const long idx = zC * slab + grow * ldc + gcol;
                    ((float*)C)[idx] = 0.7f * base[idx] + 0.3f * v;
                    const long tidx = zOT * slab + gcol * (long)ldt + grow;
                    OT[tidx] = 0.7f * accB[tidx] + 0.3f * v;
                } else if constexpr (EPI == 6) {
                    const int sec = (int)(gcol >> 10);            // uniform per block
                    if (sec == 0) {
                        ((u16*)C)[grow * 1024 + gcol] = f2bf(v);                  // K_conv
                    } else if (sec == 1) {
                        const long col = gcol - 1024;
                        ((u16*)Cx)[(grow >> 11) * 2097152 + col * 2048 + (grow & 2047)] = f2bf(v); // VT_conv
                    } else {
                        ((u16*)Cy)[grow * 1024 + (gcol - 2048)] = f2bf(v);        // Q_emer
                    }
                } else {  // EPI == 7
                    const int sec = (int)(gcol >> 10);
                    if (sec == 0) {
                        ((u16*)C)[grow * 1024 + gcol] = f2bf(v);                  // Q_conv
                    } else if (sec == 1) {
                        ((u16*)Cx)[grow * 1024 + (gcol - 1024)] = f2bf(v);        // K_emer
                    } else {
                        const long col = gcol - 2048;
                        ((u16*)Cy)[(grow >> 8) * 262144 + col * 256 + (grow & 255)] = f2bf(v);     // VT_emer
                    }
                }
            }
        }
    }
}

// ---------------------------------------------------------------------------
// softmax + gate + renorm, IN PLACE on bf16 scores; one wave per row.
// ---------------------------------------------------------------------------
template<int NU2>
__global__ void __launch_bounds__(256) softmax_gate_kernel(
    u16* __restrict__ P,
    const float* __restrict__ AG, const float* __restrict__ EG, int qmask)
{
    const int row = blockIdx.x * 4 + (threadIdx.x >> 6);
    const int lane = threadIdx.x & 63;
    const int q = row & qmask;
    unsigned* pr = (unsigned*)(P + (long)row * (NU2 * 128));
    float r0[NU2], r1[NU2];
    float m = -3.4e38f;
    #pragma unroll
    for (int u = 0; u < NU2; ++u) {
        unsigned v = pr[lane + 64 * u];
        r0[u] = bf2f((u16)(v & 0xffffu));
        r1[u] = bf2f((u16)(v >> 16));
        m = fmaxf(m, fmaxf(r0[u], r1[u]));
    }
    for (int o = 32; o > 0; o >>= 1) m = fmaxf(m, __shfl_xor(m, o));
    float l = 0.0f, se = 0.0f;
    #pragma unroll
    for (int u = 0; u < NU2; ++u) {
        float e0 = __expf(r0[u] - m), e1 = __expf(r1[u] - m);
        l += e0 + e1;
        float2 eg = *(const float2*)(EG + 2 * (lane + 64 * u));
        r0[u] = e0 * eg.x; r1[u] = e1 * eg.y;
        se += r0[u] + r1[u];
    }
    for (int o = 32; o > 0; o >>= 1) { l += __shfl_xor(l, o); se += __shfl_xor(se, o); }
    const float ag = AG[q];
    const float f = ag / (ag * se + l * 1e-8f);
    #pragma unroll
    for (int u = 0; u < NU2; ++u) {
        unsigned vo = (unsigned)f2bf(r0[u] * f) | ((unsigned)f2bf(r1[u] * f) << 16);
        pr[lane + 64 * u] = vo;
    }
}

__global__ void __launch_bounds__(256) rowmean_sig_kernel(
    const float* __restrict__ X, int len, float invlen,
    const float* __restrict__ alpha_p, float* __restrict__ OUT)
{
    const int row = blockIdx.x * 4 + (threadIdx.x >> 6);
    const int lane = threadIdx.x & 63;
    const float* xr = X + (long)row * len;
    float s = 0.0f;
    for (int k = lane; k < len; k += 64) s += xr[k];
    for (int o = 32; o > 0; o >>= 1) s += __shfl_xor(s, o);
    if (lane == 0) OUT[row] = sigmoidf_((*alpha_p) * s * invlen);
}

#define MFMA_TAIL nullptr, nullptr, nullptr, nullptr, 0L, 0

extern "C" void kernel_launch(void* const* d_in, const int* in_sizes, int n_in,
                              void* d_out, int out_size, void* d_ws, size_t ws_size,
                              hipStream_t stream)
{
    (void)in_sizes; (void)n_in; (void)out_size; (void)ws_size;
    const float* o_micro    = (const float*)d_in[0];
    const float* o_macro    = (const float*)d_in[1];
    const float* r_conv_acc = (const float*)d_in[2];
    const float* r_emer_acc = (const float*)d_in[3];
    const float* ln_u_w = (const float*)d_in[4];
    const float* ln_u_b = (const float*)d_in[5];
    const float* bw_u   = (const float*)d_in[6];
    const float* ln_m_w = (const float*)d_in[7];
    const float* ln_m_b = (const float*)d_in[8];
    const float* bw_m   = (const float*)d_in[9];
    const float* gu_w   = (const float*)d_in[10];
    const float* gu_b   = (const float*)d_in[11];
    const float* gm_w   = (const float*)d_in[12];
    const float* gm_b   = (const float*)d_in[13];
    const float* wq_c   = (const float*)d_in[14];
    const float* wk_c   = (const float*)d_in[15];
    const float* wv_c   = (const float*)d_in[16];
    const float* wo_c   = (const float*)d_in[17];
    const float* wq_e   = (const float*)d_in[18];
    const float* wk_e   = (const float*)d_in[19];
    const float* wv_e   = (const float*)d_in[20];
    const float* wo_e   = (const float*)d_in[21];
    const float* res_alpha = (const float*)d_in[22];

    float* out = (float*)d_out;
    float* out_micro = out;              // (4,2048,1024)
    float* out_macro = out + 8388608;    // (4,256,1024)
    float* out_rconv = out + 9437184;    // (4,256,2048)
    float* out_remer = out + 11534336;   // (4,2048,256)

    // workspace (f32 slot offsets; bf16 buffers use 2 el/slot)
    float* ws = (float*)d_ws;
    u16* OUb = (u16*)ws;                       // 8388608 bf16 (normed micro)
    u16* OMb = (u16*)(ws + 4194304);           // 1048576 bf16 (normed macro)
    u16* WB  = (u16*)(ws + 4718592);           // 8 x 1048576 bf16 weights
                                               //   [wk_c wv_c wq_e | wq_c wk_e wv_e | wo_c wo_e]
    u16* Kcb = (u16*)(ws + 8912896);           // conv K (8192x1024) -> later CTe
    u16* VTc = (u16*)(ws + 13107200);          // conv V^T [b][h][64][2048]
    u16* Qeb = (u16*)(ws + 17301504);          // emer Q (8192x1024)
    u16* Qcb = (u16*)(ws + 21495808);          // conv Q (1024x1024) -> later CTb
    u16* Keb = (u16*)(ws + 22020096);          // emer K (1024x1024)
    u16* VTe = (u16*)(ws + 22544384);          // emer V^T [b][h][64][256]
    u16* PNu = (u16*)(ws + 23068672);          // pairnormed micro (8.4M bf16)
    float* CT = ws + 27262976;                 // conv ctx f32 (4x256x1024); early: PNm
    float* GU = ws + 28311552;                 // 8192
    float* GM = GU + 8192;                     // 1024
    float* RCS = GM + 1024;                    // 1024
    float* RES = RCS + 1024;                   // 8192
    u16* PNm = (u16*)CT;
    u16* CTb = Qcb;
    u16* CTe = Kcb;
    u16* SCu = (u16*)out_micro;                // per-batch bf16 score/prob slab

    // 1. weights -> bf16, reordered for fused projections
    wconv_kernel<<<dim3(1024, 8), 256, 0, stream>>>(wk_c, wv_c, wq_e, wq_c, wk_e, wv_e, wo_c, wo_e, WB);
    // 2. balance norms + gates + fused pairnorm
    norm_gate_kernel<<<8192, 256, 0, stream>>>(o_micro, ln_u_w, ln_u_b, bw_u, gu_w, gu_b, OUb, PNu, GU);
    norm_gate_kernel<<<1024, 256, 0, stream>>>(o_macro, ln_m_w, ln_m_b, bw_m, gm_w, gm_b, OMb, PNm, GM);
    // 3. resonance GEMM + 0.7/0.3 blend + transposed write
    mfma_nt<128, 5, false><<<dim3(16, 2, 4), 256, 0, stream>>>(
        PNm, 262144L, PNu, 2097152L, out_rconv, 524288L, nullptr, nullptr,
        1024, 1024, 1024, 2048, 1.0f / 512.0f, 1,
        r_conv_acc, nullptr, r_emer_acc, out_remer, 524288L, 256);
    // 4. resonance scalars
    rowmean_sig_kernel<<<256, 256, 0, stream>>>(out_rconv, 2048, 1.0f / 2048.0f, res_alpha, RCS);
    rowmean_sig_kernel<<<2048, 256, 0, stream>>>(out_remer, 256, 1.0f / 256.0f, res_alpha, RES);
    // 5. fused micro-side projections: [K_conv | VT_conv | Q_emer]
    mfma_nt<128, 6, true><<<dim3(24, 64, 1), 256, 0, stream>>>(
        OUb, 0L, WB, 0L, Kcb, 0L, VTc, Qeb,
        1024, 1024, 1024, 1024, 1.0f, 1, MFMA_TAIL);
    // 6. fused macro-side projections: [Q_conv | K_emer | VT_emer]
    mfma_nt<128, 7, true><<<dim3(24, 8, 1), 256, 0, stream>>>(
        OMb, 0L, WB + 3 * 1048576, 0L, Qcb, 0L, Keb, VTe,
        1024, 1024, 1024, 1024, 1.0f, 1, MFMA_TAIL);
    // 7. conv ctx accumulator
    (void)hipMemsetAsync(CT, 0, 1048576 * sizeof(float), stream);
    // 8. conv attention per batch (bf16 scores in place in SCu)
    for (int b = 0; b < 4; ++b) {
        mfma_nt<128, 0, false><<<dim3(16, 2, 16), 256, 0, stream>>>(
            Qcb + (long)b * 262144, 64L, Kcb + (long)b * 2097152, 64L, SCu, 524288L, nullptr, nullptr,
            64, 1024, 1024, 2048, 0.125f, 1, MFMA_TAIL);
        softmax_gate_kernel<16><<<1024, 256, 0, stream>>>(SCu, GM + b * 256, GU + b * 2048, 255);
        mfma_nt<64, 2, false><<<dim3(1, 2, 128), 256, 0, stream>>>(
            SCu, 524288L, VTc + (long)b * 2097152, 131072L, (void*)(CT + (long)b * 262144), 64L, nullptr, nullptr,
            2048, 2048, 2048, 1024, 1.0f, 8, MFMA_TAIL);
    }
    // 9-10. conv out-proj + residual + r_conv_scalar -> o_macro_new
    cvt_kernel<<<1024, 256, 0, stream>>>(CT, CTb);
    mfma_nt<128, 3, false><<<dim3(8, 8, 1), 256, 0, stream>>>(
        CTb, 0L, WB + 6 * 1048576, 0L, out_macro, 0L, nullptr, nullptr,
        1024, 1024, 1024, 1024, 1.0f, 1, o_macro, RCS, nullptr, nullptr, 0L, 0);
    // 11. emer attention per batch
    for (int b = 0; b < 4; ++b) {
        mfma_nt<128, 0, false><<<dim3(2, 16, 16), 256, 0, stream>>>(
            Qeb + (long)b * 2097152, 64L, Keb + (long)b * 262144, 64L, SCu, 524288L, nullptr, nullptr,
            64, 1024, 1024, 256, 0.125f, 1, MFMA_TAIL);
        softmax_gate_kernel<2><<<8192, 256, 0, stream>>>(SCu, GU + b * 2048, GM + b * 256, 2047);
        mfma_nt<64, 0, false><<<dim3(1, 16, 16), 256, 0, stream>>>(
            SCu, 524288L, VTe + (long)b * 262144, 16384L, (void*)(CTe + (long)b * 2097152), 64L, nullptr, nullptr,
            256, 256, 256, 1024, 1.0f, 1, MFMA_TAIL);
    }
    // 12. emer out-proj + residual + r_emer_scalar -> o_micro_new
    mfma_nt<128, 3, true><<<dim3(8, 64, 1), 256, 0, stream>>>(
        CTe, 0L, WB + 7 * 1048576, 0L, out_micro, 0L, nullptr, nullptr,
        1024, 1024, 1024, 1024, 1.0f, 1, o_micro, RES, nullptr, nullptr, 0L, 0);
}

// Round 5
// 498.490 us; speedup vs baseline: 1.4106x; 1.1552x over previous
//
#include <hip/hip_runtime.h>
#include <math.h>

// B=4, TU=2048, TM=256, D=1024, H=16, DH=64, PAIRS=512
typedef unsigned short u16;
typedef __attribute__((ext_vector_type(8))) short bf16x8;
typedef __attribute__((ext_vector_type(4))) float f32x4;

__device__ __forceinline__ float sigmoidf_(float x) { return 1.0f / (1.0f + __expf(-x)); }
__device__ __forceinline__ u16 f2bf(float v) {
    union { float f; unsigned u; } x; x.f = v;
    unsigned r = x.u + 0x7fffu + ((x.u >> 16) & 1u);
    return (u16)(r >> 16);
}
__device__ __forceinline__ float bf2f(u16 u) {
    union { unsigned u; float f; } x; x.u = ((unsigned)u) << 16; return x.f;
}

// ---------------------------------------------------------------------------
// balance_norm + gate + fused pair(phase)-normalization.
// ---------------------------------------------------------------------------
__global__ void __launch_bounds__(256) norm_gate_kernel(
    const float* __restrict__ X,
    const float* __restrict__ w, const float* __restrict__ bvec,
    const float* __restrict__ bw_p,
    const float* __restrict__ gw, const float* __restrict__ gb_p,
    u16* __restrict__ OUT, u16* __restrict__ PN, float* __restrict__ G)
{
    const int row = blockIdx.x;
    const int t = threadIdx.x;
    const float* xr = X + (size_t)row * 1024;
    float4 x4 = *(const float4*)(xr + 4 * t);
    __shared__ float sh1[256], sh2[256];
    sh1[t] = x4.x + x4.y + x4.z + x4.w;
    sh2[t] = x4.x * x4.x + x4.y * x4.y + x4.z * x4.z + x4.w * x4.w;
    __syncthreads();
    for (int o = 64; o > 0; o >>= 1) {
        if ((t & 127) < o) sh2[t] += sh2[t + o];
        __syncthreads();
    }
    const float slo = sh2[0], shi = sh2[128];
    for (int o = 128; o > 0; o >>= 1) {
        if (t < o) sh1[t] += sh1[t + o];
        __syncthreads();
    }
    const float mu = sh1[0] * (1.0f / 1024.0f);
    const float var = (slo + shi) * (1.0f / 1024.0f) - mu * mu;
    const float rstd = rsqrtf(var + 1e-6f);
    const float imb = (slo - shi) * (1.0f / 512.0f) * (*bw_p);
    const float corr = (t < 128) ? -imb : imb;
    const int i0 = 4 * t;
    float o0 = (x4.x - mu) * rstd * w[i0 + 0] + bvec[i0 + 0] + corr;
    float o1 = (x4.y - mu) * rstd * w[i0 + 1] + bvec[i0 + 1] + corr;
    float o2 = (x4.z - mu) * rstd * w[i0 + 2] + bvec[i0 + 2] + corr;
    float o3 = (x4.w - mu) * rstd * w[i0 + 3] + bvec[i0 + 3] + corr;
    float gd = o0 * gw[i0 + 0] + o1 * gw[i0 + 1] + o2 * gw[i0 + 2] + o3 * gw[i0 + 3];
    __syncthreads();
    sh1[t] = gd;
    __syncthreads();
    for (int o = 128; o > 0; o >>= 1) {
        if (t < o) sh1[t] += sh1[t + o];
        __syncthreads();
    }
    if (t == 0) G[row] = sigmoidf_(sh1[0] + *gb_p);
    u16 ob[4] = { f2bf(o0), f2bf(o1), f2bf(o2), f2bf(o3) };
    *(uint2*)(OUT + (size_t)row * 1024 + i0) = *(uint2*)ob;
    float pa = o0 + 1e-8f, pb = o1 + 1e-8f;
    float r0 = rsqrtf(pa * pa + pb * pb);
    float pc = o2 + 1e-8f, pd = o3 + 1e-8f;
    float r1 = rsqrtf(pc * pc + pd * pd);
    u16 pn[4] = { f2bf(pa * r0), f2bf(pb * r0), f2bf(pc * r1), f2bf(pd * r1) };
    *(uint2*)(PN + (size_t)row * 1024 + i0) = *(uint2*)pn;
}

// ---------------------------------------------------------------------------
// weight fp32 -> bf16 (8 slots of 1M elements; order set by pointer args)
// ---------------------------------------------------------------------------
__global__ void __launch_bounds__(256) wconv_kernel(
    const float* w0, const float* w1, const float* w2, const float* w3,
    const float* w4, const float* w5, const float* w6, const float* w7,
    u16* __restrict__ dst)
{
    const float* s;
    switch (blockIdx.y) {
        case 0: s = w0; break; case 1: s = w1; break;
        case 2: s = w2; break; case 3: s = w3; break;
        case 4: s = w4; break; case 5: s = w5; break;
        case 6: s = w6; break; default: s = w7; break;
    }
    long i = (long)blockIdx.x * 1024 + threadIdx.x * 4;
    float4 v = *(const float4*)(s + i);
    u16 o[4] = { f2bf(v.x), f2bf(v.y), f2bf(v.z), f2bf(v.w) };
    *(uint2*)(dst + (long)blockIdx.y * 1048576 + i) = *(uint2*)o;
}

__global__ void __launch_bounds__(256) cvt_kernel(const float* __restrict__ S, u16* __restrict__ D)
{
    long i = ((long)blockIdx.x * 256 + threadIdx.x) * 4;
    float4 v = *(const float4*)(S + i);
    u16 o[4] = { f2bf(v.x), f2bf(v.y), f2bf(v.z), f2bf(v.w) };
    *(uint2*)(D + i) = *(uint2*)o;
}

// ---------------------------------------------------------------------------
// bf16 NT MFMA GEMM, 128xBN tile, BK=32, 256 threads (2x2 waves).
// COUNTED-VMCNT 2-phase pipeline (T4): stage k+1, then s_waitcnt vmcnt(LPS)
// (k's loads done, k+1's stay IN FLIGHT) + raw s_barrier; ds_read; then
// lgkmcnt(0) + raw s_barrier protects the buffer re-staged next iter.
// LDS in MFMA-fragment order (m173): conflict-free ds_read_b128.
// Slab addressing: z -> (slab, ks); slab -> (b = slab/nH, h = slab%nH);
// operand offset = b*z?b + h*z?h. SWZ: bijective XCD swizzle (m204).
// EPI 0: bf16 store                 2: f32 atomicAdd
//     3: f32 base[idx]+acc*rs[m]    5: resonance blend + transposed write
//     6: micro fused 3-way (Kc | VTc transposed | Qe)
//     7: macro fused 3-way (Qc | Ke | VTe transposed)
// ---------------------------------------------------------------------------
template<int BN, int EPI, bool SWZ>
__global__ void __launch_bounds__(256) mfma_nt(
    const u16* __restrict__ A, long zAb, long zAh,
    const u16* __restrict__ B, long zBb, long zBh,
    void* __restrict__ C, long zCb, long zCh,
    void* __restrict__ Cx, void* __restrict__ Cy,
    int K, int lda, int ldb, int ldc, float alpha, int nH, int nsplit,
    const float* __restrict__ base, const float* __restrict__ rs,
    const float* __restrict__ accB, float* __restrict__ OT,
    long zOT, int ldt)
{
    constexpr int NR = BN / 32;
    __shared__ __align__(16) u16 As[2][128 * 32];
    __shared__ __align__(16) u16 Bs[2][BN * 32];
    int bx, by, bz;
    if constexpr (SWZ) {
        const int gx = gridDim.x, gy = gridDim.y;
        const int nwg = gx * gy * gridDim.z;
        const int lin = blockIdx.x + gx * (blockIdx.y + gy * blockIdx.z);
        const int q8 = nwg >> 3, r8 = nwg & 7;
        const int xcd = lin & 7, off = lin >> 3;
        const int swz = (xcd < r8 ? xcd * (q8 + 1) : r8 * (q8 + 1) + (xcd - r8) * q8) + off;
        bx = swz % gx;
        const int tmp = swz / gx;
        by = tmp % gy;
        bz = tmp / gy;
    } else {
        bx = blockIdx.x; by = blockIdx.y; bz = blockIdx.z;
    }
    const int t = threadIdx.x;
    const int lane = t & 63, w = t >> 6;
    const int wr = w >> 1, wc = w & 1;
    const int slab = bz / nsplit, ks = bz - slab * nsplit;
    const int b = slab / nH, h = slab - b * nH;
    const int kchunk = K / nsplit;
    const int kbeg = ks * kchunk, kend = kbeg + kchunk;
    const long m0 = (long)by * 128;
    const long n0 = (long)bx * BN;
    const int frow = lane & 15, fko = (lane >> 4) * 8;
    const u16* gaA = A + zAb * b + zAh * h + (m0 + 32 * w + frow) * lda + fko;
    const u16* gbB;
    if constexpr (BN == 128) gbB = B + zBb * b + zBh * h + (n0 + 32 * w + frow) * ldb + fko;
    else                     gbB = B + zBb * b + zBh * h + (n0 + 16 * w + frow) * ldb + fko;

#define GLD(src, dst) __builtin_amdgcn_global_load_lds( \
        (const __attribute__((address_space(1))) void*)(src), \
        (__attribute__((address_space(3))) void*)(dst), 16, 0, 0)

    auto stage = [&](int kk, int p) {
        GLD(gaA + kk, &As[p][2 * w * 512]);
        GLD(gaA + 16L * lda + kk, &As[p][(2 * w + 1) * 512]);
        if constexpr (BN == 128) {
            GLD(gbB + kk, &Bs[p][2 * w * 512]);
            GLD(gbB + 16L * ldb + kk, &Bs[p][(2 * w + 1) * 512]);
        } else {
            GLD(gbB + kk, &Bs[p][w * 512]);
        }
    };

    f32x4 acc[4][NR] = {};
    stage(kbeg, 0);
    int cur = 0;
    for (int k0 = kbeg; k0 < kend; k0 += 32) {
        if (k0 + 32 < kend) {
            stage(k0 + 32, cur ^ 1);
            // wait only for tile-k's loads; k+1's stay in flight across barrier
            if constexpr (BN == 128) asm volatile("s_waitcnt vmcnt(4)" ::: "memory");
            else                     asm volatile("s_waitcnt vmcnt(3)" ::: "memory");
        } else {
            asm volatile("s_waitcnt vmcnt(0)" ::: "memory");
        }
        __builtin_amdgcn_sched_barrier(0);
        __builtin_amdgcn_s_barrier();           // tile k visible to all waves
        bf16x8 af[4], bfr[NR];
        #pragma unroll
        for (int m = 0; m < 4; ++m)
            af[m] = *(const bf16x8*)(&As[cur][(wr * 4 + m) * 512 + lane * 8]);
        #pragma unroll
        for (int n = 0; n < NR; ++n)
            bfr[n] = *(const bf16x8*)(&Bs[cur][(wc * NR + n) * 512 + lane * 8]);
        asm volatile("s_waitcnt lgkmcnt(0)" ::: "memory");
        __builtin_amdgcn_sched_barrier(0);
        __builtin_amdgcn_s_barrier();           // all reads done; buf may be re-staged
        #pragma unroll
        for (int m = 0; m < 4; ++m)
            #pragma unroll
            for (int n = 0; n < NR; ++n)
                acc[m][n] = __builtin_amdgcn_mfma_f32_16x16x32_bf16(af[m], bfr[n], acc[m][n], 0, 0, 0);
        cur ^= 1;
    }
#undef GLD
    const long Coff = zCb * b + zCh * h;
    const int l15 = lane & 15, l4 = lane >> 4;
    #pragma unroll
    for (int m = 0; m < 4; ++m) {
        #pragma unroll
        for (int n = 0; n < NR; ++n) {
            #pragma unroll
            for (int j = 0; j < 4; ++j) {
                const long grow = m0 + wr * 64 + m * 16 + l4 * 4 + j;
                const long gcol = n0 + wc * (BN / 2) + n * 16 + l15;
                const float v = acc[m][n][j] * alpha;
                if constexpr (EPI == 0) {
                    ((u16*)C)[Coff + grow * ldc + gcol] = f2bf(v);
                } else if constexpr (EPI == 2) {
                    atomicAdd((float*)C + Coff + grow * ldc + gcol, v);
                } else if constexpr (EPI == 3) {
                    const long idx = grow * ldc + gcol;
                    ((float*)C)[idx] = base[idx] + v * rs[grow];
                } else if constexpr (EPI == 5) {
                    const long idx = Coff + grow * ldc + gcol;
                    ((float*)C)[idx] = 0.7f * base[idx] + 0.3f * v;
                    const long tidx = zOT * b + gcol * (long)ldt + grow;
                    OT[tidx] = 0.7f * accB[tidx] + 0.3f * v;
                } else if constexpr (EPI == 6) {
                    const int sec = (int)(gcol >> 10);            // uniform per block
                    if (sec == 0) {
                        ((u16*)C)[grow * 1024 + gcol] = f2bf(v);                  // K_conv
                    } else if (sec == 1) {
                        const long col = gcol - 1024;
                        ((u16*)Cx)[(grow >> 11) * 2097152 + col * 2048 + (grow & 2047)] = f2bf(v); // VT_conv
                    } else {
                        ((u16*)Cy)[grow * 1024 + (gcol - 2048)] = f2bf(v);        // Q_emer
                    }
                } else {  // EPI == 7
                    const int sec = (int)(gcol >> 10);
                    if (sec == 0) {
                        ((u16*)C)[grow * 1024 + gcol] = f2bf(v);                  // Q_conv
                    } else if (sec == 1) {
                        ((u16*)Cx)[grow * 1024 + (gcol - 1024)] = f2bf(v);        // K_emer
                    } else {
                        const long col = gcol - 2048;
                        ((u16*)Cy)[(grow >> 8) * 262144 + col * 256 + (grow & 255)] = f2bf(v);     // VT_emer
                    }
                }
            }
        }
    }
}

// ---------------------------------------------------------------------------
// softmax + gate + renorm, IN PLACE on bf16 scores; one wave per row.
// Multi-batch: b_local = row>>bshift; ag = AG[b_local*qld + (row&qmask)];
// eg row base = EG + b_local*egld.
// ---------------------------------------------------------------------------
template<int NU2>
__global__ void __launch_bounds__(256) softmax_gate_kernel(
    u16* __restrict__ P,
    const float* __restrict__ AG, const float* __restrict__ EG,
    int bshift, int qmask, int qld, int egld)
{
    const int row = blockIdx.x * 4 + (threadIdx.x >> 6);
    const int lane = threadIdx.x & 63;
    const int bl = row >> bshift;
    unsigned* pr = (unsigned*)(P + (long)row * (NU2 * 128));
    const float* egr = EG + (long)bl * egld;
    float r0[NU2], r1[NU2];
    float m = -3.4e38f;
    #pragma unroll
    for (int u = 0; u < NU2; ++u) {
        unsigned v = pr[lane + 64 * u];
        r0[u] = bf2f((u16)(v & 0xffffu));
        r1[u] = bf2f((u16)(v >> 16));
        m = fmaxf(m, fmaxf(r0[u], r1[u]));
    }
    for (int o = 32; o > 0; o >>= 1) m = fmaxf(m, __shfl_xor(m, o));
    float l = 0.0f, se = 0.0f;
    #pragma unroll
    for (int u = 0; u < NU2; ++u) {
        float e0 = __expf(r0[u] - m), e1 = __expf(r1[u] - m);
        l += e0 + e1;
        float2 eg = *(const float2*)(egr + 2 * (lane + 64 * u));
        r0[u] = e0 * eg.x; r1[u] = e1 * eg.y;
        se += r0[u] + r1[u];
    }
    for (int o = 32; o > 0; o >>= 1) { l += __shfl_xor(l, o); se += __shfl_xor(se, o); }
    const float ag = AG[(long)bl * qld + (row & qmask)];
    const float f = ag / (ag * se + l * 1e-8f);
    #pragma unroll
    for (int u = 0; u < NU2; ++u) {
        unsigned vo = (unsigned)f2bf(r0[u] * f) | ((unsigned)f2bf(r1[u] * f) << 16);
        pr[lane + 64 * u] = vo;
    }
}

__global__ void __launch_bounds__(256) rowmean_sig_kernel(
    const float* __restrict__ X, int len, float invlen,
    const float* __restrict__ alpha_p, float* __restrict__ OUT)
{
    const int row = blockIdx.x * 4 + (threadIdx.x >> 6);
    const int lane = threadIdx.x & 63;
    const float* xr = X + (long)row * len;
    float s = 0.0f;
    for (int k = lane; k < len; k += 64) s += xr[k];
    for (int o = 32; o > 0; o >>= 1) s += __shfl_xor(s, o);
    if (lane == 0) OUT[row] = sigmoidf_((*alpha_p) * s * invlen);
}

#define MFMA_TAIL nullptr, nullptr, nullptr, nullptr, 0L, 0

extern "C" void kernel_launch(void* const* d_in, const int* in_sizes, int n_in,
                              void* d_out, int out_size, void* d_ws, size_t ws_size,
                              hipStream_t stream)
{
    (void)in_sizes; (void)n_in; (void)out_size; (void)ws_size;
    const float* o_micro    = (const float*)d_in[0];
    const float* o_macro    = (const float*)d_in[1];
    const float* r_conv_acc = (const float*)d_in[2];
    const float* r_emer_acc = (const float*)d_in[3];
    const float* ln_u_w = (const float*)d_in[4];
    const float* ln_u_b = (const float*)d_in[5];
    const float* bw_u   = (const float*)d_in[6];
    const float* ln_m_w = (const float*)d_in[7];
    const float* ln_m_b = (const float*)d_in[8];
    const float* bw_m   = (const float*)d_in[9];
    const float* gu_w   = (const float*)d_in[10];
    const float* gu_b   = (const float*)d_in[11];
    const float* gm_w   = (const float*)d_in[12];
    const float* gm_b   = (const float*)d_in[13];
    const float* wq_c   = (const float*)d_in[14];
    const float* wk_c   = (const float*)d_in[15];
    const float* wv_c   = (const float*)d_in[16];
    const float* wo_c   = (const float*)d_in[17];
    const float* wq_e   = (const float*)d_in[18];
    const float* wk_e   = (const float*)d_in[19];
    const float* wv_e   = (const float*)d_in[20];
    const float* wo_e   = (const float*)d_in[21];
    const float* res_alpha = (const float*)d_in[22];

    float* out = (float*)d_out;
    float* out_micro = out;              // (4,2048,1024)
    float* out_macro = out + 8388608;    // (4,256,1024)
    float* out_rconv = out + 9437184;    // (4,256,2048)
    float* out_remer = out + 11534336;   // (4,2048,256)

    // workspace (f32 slot offsets; bf16 buffers use 2 el/slot)
    float* ws = (float*)d_ws;
    u16* OUb = (u16*)ws;                       // 8388608 bf16 (normed micro)
    u16* OMb = (u16*)(ws + 4194304);           // 1048576 bf16 (normed macro)
    u16* WB  = (u16*)(ws + 4718592);           // 8 x 1048576 bf16 weights
                                               //   [wk_c wv_c wq_e | wq_c wk_e wv_e | wo_c wo_e]
    u16* Kcb = (u16*)(ws + 8912896);           // conv K (8192x1024) -> later CTe
    u16* VTc = (u16*)(ws + 13107200);          // conv V^T [b][h][64][2048]
    u16* Qeb = (u16*)(ws + 17301504);          // emer Q (8192x1024)
    u16* Qcb = (u16*)(ws + 21495808);          // conv Q (1024x1024) -> later CTb
    u16* Keb = (u16*)(ws + 22020096);          // emer K (1024x1024)
    u16* VTe = (u16*)(ws + 22544384);          // emer V^T [b][h][64][256]
    u16* PNu = (u16*)(ws + 23068672);          // pairnormed micro (8.4M bf16)
    float* CT = ws + 27262976;                 // conv ctx f32 (4x256x1024); early: PNm
    float* GU = ws + 28311552;                 // 8192
    float* GM = GU + 8192;                     // 1024
    float* RCS = GM + 1024;                    // 1024
    float* RES = RCS + 1024;                   // 8192
    u16* PNm = (u16*)CT;
    u16* CTb = Qcb;
    u16* CTe = Kcb;
    u16* SCu = (u16*)out_micro;                // 2-batch bf16 score/prob slab (16.8M els)

    // 1. weights -> bf16, reordered for fused projections
    wconv_kernel<<<dim3(1024, 8), 256, 0, stream>>>(wk_c, wv_c, wq_e, wq_c, wk_e, wv_e, wo_c, wo_e, WB);
    // 2. balance norms + gates + fused pairnorm
    norm_gate_kernel<<<8192, 256, 0, stream>>>(o_micro, ln_u_w, ln_u_b, bw_u, gu_w, gu_b, OUb, PNu, GU);
    norm_gate_kernel<<<1024, 256, 0, stream>>>(o_macro, ln_m_w, ln_m_b, bw_m, gm_w, gm_b, OMb, PNm, GM);
    // 3. resonance GEMM + 0.7/0.3 blend + transposed write
    mfma_nt<128, 5, false><<<dim3(16, 2, 4), 256, 0, stream>>>(
        PNm, 262144L, 0L, PNu, 2097152L, 0L, out_rconv, 524288L, 0L, nullptr, nullptr,
        1024, 1024, 1024, 2048, 1.0f / 512.0f, 1, 1,
        r_conv_acc, nullptr, r_emer_acc, out_remer, 524288L, 256);
    // 4. resonance scalars
    rowmean_sig_kernel<<<256, 256, 0, stream>>>(out_rconv, 2048, 1.0f / 2048.0f, res_alpha, RCS);
    rowmean_sig_kernel<<<2048, 256, 0, stream>>>(out_remer, 256, 1.0f / 256.0f, res_alpha, RES);
    // 5. fused micro-side projections: [K_conv | VT_conv | Q_emer]
    mfma_nt<128, 6, true><<<dim3(24, 64, 1), 256, 0, stream>>>(
        OUb, 0L, 0L, WB, 0L, 0L, Kcb, 0L, 0L, VTc, Qeb,
        1024, 1024, 1024, 1024, 1.0f, 1, 1, MFMA_TAIL);
    // 6. fused macro-side projections: [Q_conv | K_emer | VT_emer]
    mfma_nt<128, 7, true><<<dim3(24, 8, 1), 256, 0, stream>>>(
        OMb, 0L, 0L, WB + 3 * 1048576, 0L, 0L, Qcb, 0L, 0L, Keb, VTe,
        1024, 1024, 1024, 1024, 1.0f, 1, 1, MFMA_TAIL);
    // 7. conv ctx accumulator
    (void)hipMemsetAsync(CT, 0, 1048576 * sizeof(float), stream);
    // 8. conv attention, 2 batches per dispatch
    for (int p = 0; p < 2; ++p) {
        mfma_nt<128, 0, false><<<dim3(16, 2, 32), 256, 0, stream>>>(
            Qcb + (long)p * 524288, 262144L, 64L,
            Kcb + (long)p * 4194304, 2097152L, 64L,
            SCu, 8388608L, 524288L, nullptr, nullptr,
            64, 1024, 1024, 2048, 0.125f, 16, 1, MFMA_TAIL);
        softmax_gate_kernel<16><<<2048, 256, 0, stream>>>(
            SCu, GM + p * 512, GU + p * 4096, 12, 255, 256, 2048);
        mfma_nt<64, 2, false><<<dim3(1, 2, 256), 256, 0, stream>>>(
            SCu, 8388608L, 524288L,
            VTc + (long)p * 4194304, 2097152L, 131072L,
            (void*)(CT + (long)p * 524288), 262144L, 64L, nullptr, nullptr,
            2048, 2048, 2048, 1024, 1.0f, 16, 8, MFMA_TAIL);
    }
    // 9-10. conv out-proj + residual + r_conv_scalar -> o_macro_new
    cvt_kernel<<<1024, 256, 0, stream>>>(CT, CTb);
    mfma_nt<128, 3, false><<<dim3(8, 8, 1), 256, 0, stream>>>(
        CTb, 0L, 0L, WB + 6 * 1048576, 0L, 0L, out_macro, 0L, 0L, nullptr, nullptr,
        1024, 1024, 1024, 1024, 1.0f, 1, 1, o_macro, RCS, nullptr, nullptr, 0L, 0);
    // 11. emer attention, 2 batches per dispatch
    for (int p = 0; p < 2; ++p) {
        mfma_nt<128, 0, false><<<dim3(2, 16, 32), 256, 0, stream>>>(
            Qeb + (long)p * 4194304, 2097152L, 64L,
            Keb + (long)p * 524288, 262144L, 64L,
            SCu, 8388608L, 524288L, nullptr, nullptr,
            64, 1024, 1024, 256, 0.125f, 16, 1, MFMA_TAIL);
        softmax_gate_kernel<2><<<16384, 256, 0, stream>>>(
            SCu, GU + p * 4096, GM + p * 512, 15, 2047, 2048, 256);
        mfma_nt<64, 0, false><<<dim3(1, 16, 32), 256, 0, stream>>>(
            SCu, 8388608L, 524288L,
            VTe + (long)p * 524288, 262144L, 16384L,
            (void*)(CTe + (long)p * 4194304), 2097152L, 64L, nullptr, nullptr,
            256, 256, 256, 1024, 1.0f, 16, 1, MFMA_TAIL);
    }
    // 12. emer out-proj + residual + r_emer_scalar -> o_micro_new
    mfma_nt<128, 3, true><<<dim3(8, 64, 1), 256, 0, stream>>>(
        CTe, 0L, 0L, WB + 7 * 1048576, 0L, 0L, out_micro, 0L, 0L, nullptr, nullptr,
        1024, 1024, 1024, 1024, 1.0f, 1, 1, o_micro, RES, nullptr, nullptr, 0L, 0);
}

// Round 6
// 423.447 us; speedup vs baseline: 1.6606x; 1.1772x over previous
//
#include <hip/hip_runtime.h>
#include <math.h>

// B=4, TU=2048, TM=256, D=1024, H=16, DH=64, PAIRS=512
typedef unsigned short u16;
typedef __attribute__((ext_vector_type(8))) short bf16x8;
typedef __attribute__((ext_vector_type(4))) float f32x4;

__device__ __forceinline__ float sigmoidf_(float x) { return 1.0f / (1.0f + __expf(-x)); }
__device__ __forceinline__ u16 f2bf(float v) {
    union { float f; unsigned u; } x; x.f = v;
    unsigned r = x.u + 0x7fffu + ((x.u >> 16) & 1u);
    return (u16)(r >> 16);
}
__device__ __forceinline__ float bf2f(u16 u) {
    union { unsigned u; float f; } x; x.u = ((unsigned)u) << 16; return x.f;
}

// ---------------------------------------------------------------------------
// balance_norm + gate + fused pair(phase)-normalization.
// ---------------------------------------------------------------------------
__global__ void __launch_bounds__(256) norm_gate_kernel(
    const float* __restrict__ X,
    const float* __restrict__ w, const float* __restrict__ bvec,
    const float* __restrict__ bw_p,
    const float* __restrict__ gw, const float* __restrict__ gb_p,
    u16* __restrict__ OUT, u16* __restrict__ PN, float* __restrict__ G)
{
    const int row = blockIdx.x;
    const int t = threadIdx.x;
    const float* xr = X + (size_t)row * 1024;
    float4 x4 = *(const float4*)(xr + 4 * t);
    __shared__ float sh1[256], sh2[256];
    sh1[t] = x4.x + x4.y + x4.z + x4.w;
    sh2[t] = x4.x * x4.x + x4.y * x4.y + x4.z * x4.z + x4.w * x4.w;
    __syncthreads();
    for (int o = 64; o > 0; o >>= 1) {
        if ((t & 127) < o) sh2[t] += sh2[t + o];
        __syncthreads();
    }
    const float slo = sh2[0], shi = sh2[128];
    for (int o = 128; o > 0; o >>= 1) {
        if (t < o) sh1[t] += sh1[t + o];
        __syncthreads();
    }
    const float mu = sh1[0] * (1.0f / 1024.0f);
    const float var = (slo + shi) * (1.0f / 1024.0f) - mu * mu;
    const float rstd = rsqrtf(var + 1e-6f);
    const float imb = (slo - shi) * (1.0f / 512.0f) * (*bw_p);
    const float corr = (t < 128) ? -imb : imb;
    const int i0 = 4 * t;
    float o0 = (x4.x - mu) * rstd * w[i0 + 0] + bvec[i0 + 0] + corr;
    float o1 = (x4.y - mu) * rstd * w[i0 + 1] + bvec[i0 + 1] + corr;
    float o2 = (x4.z - mu) * rstd * w[i0 + 2] + bvec[i0 + 2] + corr;
    float o3 = (x4.w - mu) * rstd * w[i0 + 3] + bvec[i0 + 3] + corr;
    float gd = o0 * gw[i0 + 0] + o1 * gw[i0 + 1] + o2 * gw[i0 + 2] + o3 * gw[i0 + 3];
    __syncthreads();
    sh1[t] = gd;
    __syncthreads();
    for (int o = 128; o > 0; o >>= 1) {
        if (t < o) sh1[t] += sh1[t + o];
        __syncthreads();
    }
    if (t == 0) G[row] = sigmoidf_(sh1[0] + *gb_p);
    u16 ob[4] = { f2bf(o0), f2bf(o1), f2bf(o2), f2bf(o3) };
    *(uint2*)(OUT + (size_t)row * 1024 + i0) = *(uint2*)ob;
    float pa = o0 + 1e-8f, pb = o1 + 1e-8f;
    float r0 = rsqrtf(pa * pa + pb * pb);
    float pc = o2 + 1e-8f, pd = o3 + 1e-8f;
    float r1 = rsqrtf(pc * pc + pd * pd);
    u16 pn[4] = { f2bf(pa * r0), f2bf(pb * r0), f2bf(pc * r1), f2bf(pd * r1) };
    *(uint2*)(PN + (size_t)row * 1024 + i0) = *(uint2*)pn;
}

// ---------------------------------------------------------------------------
// weight fp32 -> bf16 (8 slots of 1M elements; order set by pointer args)
// ---------------------------------------------------------------------------
__global__ void __launch_bounds__(256) wconv_kernel(
    const float* w0, const float* w1, const float* w2, const float* w3,
    const float* w4, const float* w5, const float* w6, const float* w7,
    u16* __restrict__ dst)
{
    const float* s;
    switch (blockIdx.y) {
        case 0: s = w0; break; case 1: s = w1; break;
        case 2: s = w2; break; case 3: s = w3; break;
        case 4: s = w4; break; case 5: s = w5; break;
        case 6: s = w6; break; default: s = w7; break;
    }
    long i = (long)blockIdx.x * 1024 + threadIdx.x * 4;
    float4 v = *(const float4*)(s + i);
    u16 o[4] = { f2bf(v.x), f2bf(v.y), f2bf(v.z), f2bf(v.w) };
    *(uint2*)(dst + (long)blockIdx.y * 1048576 + i) = *(uint2*)o;
}

__global__ void __launch_bounds__(256) cvt_kernel(const float* __restrict__ S, u16* __restrict__ D)
{
    long i = ((long)blockIdx.x * 256 + threadIdx.x) * 4;
    float4 v = *(const float4*)(S + i);
    u16 o[4] = { f2bf(v.x), f2bf(v.y), f2bf(v.z), f2bf(v.w) };
    *(uint2*)(D + i) = *(uint2*)o;
}

// ---------------------------------------------------------------------------
// bf16 NT MFMA GEMM, 128xBN tile, BK=32, 256 threads (2x2 waves).
// 3-STAGE LDS PIPELINE, 2 TILES IN FLIGHT (T3/T4): prologue stages k0,k1;
// iter i stages i+2, then s_waitcnt vmcnt(8) (i's loads done; i+1,i+2 stay
// in flight across the barrier), ds_read, lgkmcnt(0), barrier, MFMA.
// LDS in MFMA-fragment order (m173): conflict-free ds_read_b128.
// EPI 6/7 VT sections: epilogue LDS transpose -> coalesced uint4 stores.
// EPI 0: bf16 store                 2: f32 atomicAdd
//     3: f32 base[idx]+acc*rs[m]    5: resonance blend + transposed write
//     6: micro fused 3-way (Kc | VTc transposed | Qe)
//     7: macro fused 3-way (Qc | Ke | VTe transposed)
// ---------------------------------------------------------------------------
template<int BN, int EPI, bool SWZ>
__global__ void __launch_bounds__(256) mfma_nt(
    const u16* __restrict__ A, long zAb, long zAh,
    const u16* __restrict__ B, long zBb, long zBh,
    void* __restrict__ C, long zCb, long zCh,
    void* __restrict__ Cx, void* __restrict__ Cy,
    int K, int lda, int ldb, int ldc, float alpha, int nH, int nsplit,
    const float* __restrict__ base, const float* __restrict__ rs,
    const float* __restrict__ accB, float* __restrict__ OT,
    long zOT, int ldt)
{
    constexpr int NR = BN / 32;
    constexpr int ABUF = 128 * 32;   // u16 per A stage
    constexpr int BBUF = BN * 32;    // u16 per B stage
    __shared__ __align__(16) u16 sh[3 * (ABUF + BBUF)];
    u16* const Ab0 = sh;
    u16* const Bb0 = sh + 3 * ABUF;
    int bx, by, bz;
    if constexpr (SWZ) {
        const int gx = gridDim.x, gy = gridDim.y;
        const int nwg = gx * gy * gridDim.z;
        const int lin = blockIdx.x + gx * (blockIdx.y + gy * blockIdx.z);
        const int q8 = nwg >> 3, r8 = nwg & 7;
        const int xcd = lin & 7, off = lin >> 3;
        const int swz = (xcd < r8 ? xcd * (q8 + 1) : r8 * (q8 + 1) + (xcd - r8) * q8) + off;
        bx = swz % gx;
        const int tmp = swz / gx;
        by = tmp % gy;
        bz = tmp / gy;
    } else {
        bx = blockIdx.x; by = blockIdx.y; bz = blockIdx.z;
    }
    const int t = threadIdx.x;
    const int lane = t & 63, w = t >> 6;
    const int wr = w >> 1, wc = w & 1;
    const int slab = bz / nsplit, ks = bz - slab * nsplit;
    const int b = slab / nH, h = slab - b * nH;
    const int kchunk = K / nsplit;
    const int kbeg = ks * kchunk, kend = kbeg + kchunk;
    const long m0 = (long)by * 128;
    const long n0 = (long)bx * BN;
    const int frow = lane & 15, fko = (lane >> 4) * 8;
    const u16* gaA = A + zAb * b + zAh * h + (m0 + 32 * w + frow) * lda + fko;
    const u16* gbB;
    if constexpr (BN == 128) gbB = B + zBb * b + zBh * h + (n0 + 32 * w + frow) * ldb + fko;
    else                     gbB = B + zBb * b + zBh * h + (n0 + 16 * w + frow) * ldb + fko;

#define GLD(src, dst) __builtin_amdgcn_global_load_lds( \
        (const __attribute__((address_space(1))) void*)(src), \
        (__attribute__((address_space(3))) void*)(dst), 16, 0, 0)

    auto stage = [&](int kk, int p) {
        u16* ap = Ab0 + p * ABUF;
        u16* bp = Bb0 + p * BBUF;
        GLD(gaA + kk, ap + 2 * w * 512);
        GLD(gaA + 16L * lda + kk, ap + (2 * w + 1) * 512);
        if constexpr (BN == 128) {
            GLD(gbB + kk, bp + 2 * w * 512);
            GLD(gbB + 16L * ldb + kk, bp + (2 * w + 1) * 512);
        } else {
            GLD(gbB + kk, bp + w * 512);
        }
    };

    const int nIter = (kend - kbeg) >> 5;
    f32x4 acc[4][NR] = {};
    stage(kbeg, 0);
    if (nIter > 1) stage(kbeg + 32, 1);
    int cur = 0;
    for (int i = 0; i < nIter; ++i) {
        if (i + 2 < nIter) {
            int p2 = cur + 2; if (p2 >= 3) p2 -= 3;
            stage(kbeg + (i + 2) * 32, p2);
            if constexpr (BN == 128) asm volatile("s_waitcnt vmcnt(8)" ::: "memory");
            else                     asm volatile("s_waitcnt vmcnt(6)" ::: "memory");
        } else if (i + 1 < nIter) {
            if constexpr (BN == 128) asm volatile("s_waitcnt vmcnt(4)" ::: "memory");
            else                     asm volatile("s_waitcnt vmcnt(3)" ::: "memory");
        } else {
            asm volatile("s_waitcnt vmcnt(0)" ::: "memory");
        }
        __builtin_amdgcn_sched_barrier(0);
        __builtin_amdgcn_s_barrier();        // tile i visible to all waves
        __builtin_amdgcn_sched_barrier(0);
        const u16* ap = Ab0 + cur * ABUF;
        const u16* bp = Bb0 + cur * BBUF;
        bf16x8 af[4], bfr[NR];
        #pragma unroll
        for (int m = 0; m < 4; ++m)
            af[m] = *(const bf16x8*)(ap + (wr * 4 + m) * 512 + lane * 8);
        #pragma unroll
        for (int n = 0; n < NR; ++n)
            bfr[n] = *(const bf16x8*)(bp + (wc * NR + n) * 512 + lane * 8);
        asm volatile("s_waitcnt lgkmcnt(0)" ::: "memory");
        __builtin_amdgcn_sched_barrier(0);
        __builtin_amdgcn_s_barrier();        // all reads done; buf may be re-staged
        #pragma unroll
        for (int m = 0; m < 4; ++m)
            #pragma unroll
            for (int n = 0; n < NR; ++n)
                acc[m][n] = __builtin_amdgcn_mfma_f32_16x16x32_bf16(af[m], bfr[n], acc[m][n], 0, 0, 0);
        cur = (cur == 2) ? 0 : cur + 1;
    }
#undef GLD
    const long Coff = zCb * b + zCh * h;
    const int l15 = lane & 15, l4 = lane >> 4;
    if constexpr (EPI == 6 || EPI == 7) {
        constexpr int VTSEC = (EPI == 6) ? 1 : 2;
        if ((int)(n0 >> 10) == VTSEC) {
            // transpose through LDS -> coalesced 16B stores along T
            __syncthreads();
            #pragma unroll
            for (int m = 0; m < 4; ++m)
                #pragma unroll
                for (int n = 0; n < NR; ++n)
                    #pragma unroll
                    for (int j = 0; j < 4; ++j)
                        sh[(wc * 64 + n * 16 + l15) * 136 + (wr * 64 + m * 16 + l4 * 4 + j)]
                            = f2bf(acc[m][n][j] * alpha);
            __syncthreads();
            constexpr int  LT   = (EPI == 6) ? 2048 : 256;
            constexpr int  L2T  = (EPI == 6) ? 11 : 8;
            constexpr long BSTR = (EPI == 6) ? 2097152L : 262144L;
            u16* dst = (EPI == 6) ? (u16*)Cx : (u16*)Cy;
            const long bb  = m0 >> L2T;
            const int  tt0 = (int)(m0 & (LT - 1));
            const long colb = n0 & 1023;
            #pragma unroll
            for (int it = 0; it < 8; ++it) {
                const int c = it * 16 + (t >> 4);
                const int r = (t & 15) * 8;
                uint4 v = *(const uint4*)&sh[c * 136 + r];
                *(uint4*)&dst[bb * BSTR + (colb + c) * LT + tt0 + r] = v;
            }
            return;
        }
    }
    #pragma unroll
    for (int m = 0; m < 4; ++m) {
        #pragma unroll
        for (int n = 0; n < NR; ++n) {
            #pragma unroll
            for (int j = 0; j < 4; ++j) {
                const long grow = m0 + wr * 64 + m * 16 + l4 * 4 + j;
                const long gcol = n0 + wc * (BN / 2) + n * 16 + l15;
                const float v = acc[m][n][j] * alpha;
                if constexpr (EPI == 0) {
                    ((u16*)C)[Coff + grow * ldc + gcol] = f2bf(v);
                } else if constexpr (EPI == 2) {
                    atomicAdd((float*)C + Coff + grow * ldc + gcol, v);
                } else if constexpr (EPI == 3) {
                    const long idx = grow * ldc + gcol;
                    ((float*)C)[idx] = base[idx] + v * rs[grow];
                } else if constexpr (EPI == 5) {
                    const long idx = Coff + grow * ldc + gcol;
                    ((float*)C)[idx] = 0.7f * base[idx] + 0.3f * v;
                    const long tidx = zOT * b + gcol * (long)ldt + grow;
                    OT[tidx] = 0.7f * accB[tidx] + 0.3f * v;
                } else if constexpr (EPI == 6) {
                    if (n0 < 1024) ((u16*)C)[grow * 1024 + gcol] = f2bf(v);          // K_conv
                    else           ((u16*)Cy)[grow * 1024 + (gcol - 2048)] = f2bf(v); // Q_emer
                } else {  // EPI == 7
                    if (n0 < 1024) ((u16*)C)[grow * 1024 + gcol] = f2bf(v);          // Q_conv
                    else           ((u16*)Cx)[grow * 1024 + (gcol - 1024)] = f2bf(v); // K_emer
                }
            }
        }
    }
}

// ---------------------------------------------------------------------------
// softmax + gate + renorm, IN PLACE on bf16 scores; one wave per row.
// ---------------------------------------------------------------------------
template<int NU2>
__global__ void __launch_bounds__(256) softmax_gate_kernel(
    u16* __restrict__ P,
    const float* __restrict__ AG, const float* __restrict__ EG,
    int bshift, int qmask, int qld, int egld)
{
    const int row = blockIdx.x * 4 + (threadIdx.x >> 6);
    const int lane = threadIdx.x & 63;
    const int bl = row >> bshift;
    unsigned* pr = (unsigned*)(P + (long)row * (NU2 * 128));
    const float* egr = EG + (long)bl * egld;
    float r0[NU2], r1[NU2];
    float m = -3.4e38f;
    #pragma unroll
    for (int u = 0; u < NU2; ++u) {
        unsigned v = pr[lane + 64 * u];
        r0[u] = bf2f((u16)(v & 0xffffu));
        r1[u] = bf2f((u16)(v >> 16));
        m = fmaxf(m, fmaxf(r0[u], r1[u]));
    }
    for (int o = 32; o > 0; o >>= 1) m = fmaxf(m, __shfl_xor(m, o));
    float l = 0.0f, se = 0.0f;
    #pragma unroll
    for (int u = 0; u < NU2; ++u) {
        float e0 = __expf(r0[u] - m), e1 = __expf(r1[u] - m);
        l += e0 + e1;
        float2 eg = *(const float2*)(egr + 2 * (lane + 64 * u));
        r0[u] = e0 * eg.x; r1[u] = e1 * eg.y;
        se += r0[u] + r1[u];
    }
    for (int o = 32; o > 0; o >>= 1) { l += __shfl_xor(l, o); se += __shfl_xor(se, o); }
    const float ag = AG[(long)bl * qld + (row & qmask)];
    const float f = ag / (ag * se + l * 1e-8f);
    #pragma unroll
    for (int u = 0; u < NU2; ++u) {
        unsigned vo = (unsigned)f2bf(r0[u] * f) | ((unsigned)f2bf(r1[u] * f) << 16);
        pr[lane + 64 * u] = vo;
    }
}

__global__ void __launch_bounds__(256) rowmean_sig_kernel(
    const float* __restrict__ X, int len, float invlen,
    const float* __restrict__ alpha_p, float* __restrict__ OUT)
{
    const int row = blockIdx.x * 4 + (threadIdx.x >> 6);
    const int lane = threadIdx.x & 63;
    const float* xr = X + (long)row * len;
    float s = 0.0f;
    for (int k = lane; k < len; k += 64) s += xr[k];
    for (int o = 32; o > 0; o >>= 1) s += __shfl_xor(s, o);
    if (lane == 0) OUT[row] = sigmoidf_((*alpha_p) * s * invlen);
}

#define MFMA_TAIL nullptr, nullptr, nullptr, nullptr, 0L, 0

extern "C" void kernel_launch(void* const* d_in, const int* in_sizes, int n_in,
                              void* d_out, int out_size, void* d_ws, size_t ws_size,
                              hipStream_t stream)
{
    (void)in_sizes; (void)n_in; (void)out_size; (void)ws_size;
    const float* o_micro    = (const float*)d_in[0];
    const float* o_macro    = (const float*)d_in[1];
    const float* r_conv_acc = (const float*)d_in[2];
    const float* r_emer_acc = (const float*)d_in[3];
    const float* ln_u_w = (const float*)d_in[4];
    const float* ln_u_b = (const float*)d_in[5];
    const float* bw_u   = (const float*)d_in[6];
    const float* ln_m_w = (const float*)d_in[7];
    const float* ln_m_b = (const float*)d_in[8];
    const float* bw_m   = (const float*)d_in[9];
    const float* gu_w   = (const float*)d_in[10];
    const float* gu_b   = (const float*)d_in[11];
    const float* gm_w   = (const float*)d_in[12];
    const float* gm_b   = (const float*)d_in[13];
    const float* wq_c   = (const float*)d_in[14];
    const float* wk_c   = (const float*)d_in[15];
    const float* wv_c   = (const float*)d_in[16];
    const float* wo_c   = (const float*)d_in[17];
    const float* wq_e   = (const float*)d_in[18];
    const float* wk_e   = (const float*)d_in[19];
    const float* wv_e   = (const float*)d_in[20];
    const float* wo_e   = (const float*)d_in[21];
    const float* res_alpha = (const float*)d_in[22];

    float* out = (float*)d_out;
    float* out_micro = out;              // (4,2048,1024)
    float* out_macro = out + 8388608;    // (4,256,1024)
    float* out_rconv = out + 9437184;    // (4,256,2048)
    float* out_remer = out + 11534336;   // (4,2048,256)

    // workspace (f32 slot offsets; bf16 buffers use 2 el/slot)
    float* ws = (float*)d_ws;
    u16* OUb = (u16*)ws;                       // 8388608 bf16 (normed micro)
    u16* OMb = (u16*)(ws + 4194304);           // 1048576 bf16 (normed macro)
    u16* WB  = (u16*)(ws + 4718592);           // 8 x 1048576 bf16 weights
                                               //   [wk_c wv_c wq_e | wq_c wk_e wv_e | wo_c wo_e]
    u16* Kcb = (u16*)(ws + 8912896);           // conv K (8192x1024) -> later CTe
    u16* VTc = (u16*)(ws + 13107200);          // conv V^T [b][h][64][2048]
    u16* Qeb = (u16*)(ws + 17301504);          // emer Q (8192x1024)
    u16* Qcb = (u16*)(ws + 21495808);          // conv Q (1024x1024) -> later CTb
    u16* Keb = (u16*)(ws + 22020096);          // emer K (1024x1024)
    u16* VTe = (u16*)(ws + 22544384);          // emer V^T [b][h][64][256]
    u16* PNu = (u16*)(ws + 23068672);          // pairnormed micro (8.4M bf16)
    float* CT = ws + 27262976;                 // conv ctx f32 (4x256x1024); early: PNm
    float* GU = ws + 28311552;                 // 8192
    float* GM = GU + 8192;                     // 1024
    float* RCS = GM + 1024;                    // 1024
    float* RES = RCS + 1024;                   // 8192
    u16* PNm = (u16*)CT;
    u16* CTb = Qcb;
    u16* CTe = Kcb;
    u16* SCu = (u16*)out_micro;                // 2-batch bf16 score/prob slab (16.8M els)

    // 1. weights -> bf16, reordered for fused projections
    wconv_kernel<<<dim3(1024, 8), 256, 0, stream>>>(wk_c, wv_c, wq_e, wq_c, wk_e, wv_e, wo_c, wo_e, WB);
    // 2. balance norms + gates + fused pairnorm
    norm_gate_kernel<<<8192, 256, 0, stream>>>(o_micro, ln_u_w, ln_u_b, bw_u, gu_w, gu_b, OUb, PNu, GU);
    norm_gate_kernel<<<1024, 256, 0, stream>>>(o_macro, ln_m_w, ln_m_b, bw_m, gm_w, gm_b, OMb, PNm, GM);
    // 3. resonance GEMM + 0.7/0.3 blend + transposed write
    mfma_nt<128, 5, false><<<dim3(16, 2, 4), 256, 0, stream>>>(
        PNm, 262144L, 0L, PNu, 2097152L, 0L, out_rconv, 524288L, 0L, nullptr, nullptr,
        1024, 1024, 1024, 2048, 1.0f / 512.0f, 1, 1,
        r_conv_acc, nullptr, r_emer_acc, out_remer, 524288L, 256);
    // 4. resonance scalars
    rowmean_sig_kernel<<<256, 256, 0, stream>>>(out_rconv, 2048, 1.0f / 2048.0f, res_alpha, RCS);
    rowmean_sig_kernel<<<2048, 256, 0, stream>>>(out_remer, 256, 1.0f / 256.0f, res_alpha, RES);
    // 5. fused micro-side projections: [K_conv | VT_conv | Q_emer]
    mfma_nt<128, 6, true><<<dim3(24, 64, 1), 256, 0, stream>>>(
        OUb, 0L, 0L, WB, 0L, 0L, Kcb, 0L, 0L, VTc, Qeb,
        1024, 1024, 1024, 1024, 1.0f, 1, 1, MFMA_TAIL);
    // 6. fused macro-side projections: [Q_conv | K_emer | VT_emer]
    mfma_nt<128, 7, true><<<dim3(24, 8, 1), 256, 0, stream>>>(
        OMb, 0L, 0L, WB + 3 * 1048576, 0L, 0L, Qcb, 0L, 0L, Keb, VTe,
        1024, 1024, 1024, 1024, 1.0f, 1, 1, MFMA_TAIL);
    // 7. conv ctx accumulator
    (void)hipMemsetAsync(CT, 0, 1048576 * sizeof(float), stream);
    // 8. conv attention, 2 batches per dispatch
    for (int p = 0; p < 2; ++p) {
        mfma_nt<128, 0, false><<<dim3(16, 2, 32), 256, 0, stream>>>(
            Qcb + (long)p * 524288, 262144L, 64L,
            Kcb + (long)p * 4194304, 2097152L, 64L,
            SCu, 8388608L, 524288L, nullptr, nullptr,
            64, 1024, 1024, 2048, 0.125f, 16, 1, MFMA_TAIL);
        softmax_gate_kernel<16><<<2048, 256, 0, stream>>>(
            SCu, GM + p * 512, GU + p * 4096, 12, 255, 256, 2048);
        mfma_nt<64, 2, false><<<dim3(1, 2, 256), 256, 0, stream>>>(
            SCu, 8388608L, 524288L,
            VTc + (long)p * 4194304, 2097152L, 131072L,
            (void*)(CT + (long)p * 524288), 262144L, 64L, nullptr, nullptr,
            2048, 2048, 2048, 1024, 1.0f, 16, 8, MFMA_TAIL);
    }
    // 9-10. conv out-proj + residual + r_conv_scalar -> o_macro_new
    cvt_kernel<<<1024, 256, 0, stream>>>(CT, CTb);
    mfma_nt<128, 3, false><<<dim3(8, 8, 1), 256, 0, stream>>>(
        CTb, 0L, 0L, WB + 6 * 1048576, 0L, 0L, out_macro, 0L, 0L, nullptr, nullptr,
        1024, 1024, 1024, 1024, 1.0f, 1, 1, o_macro, RCS, nullptr, nullptr, 0L, 0);
    // 11. emer attention, 2 batches per dispatch
    for (int p = 0; p < 2; ++p) {
        mfma_nt<128, 0, false><<<dim3(2, 16, 32), 256, 0, stream>>>(
            Qeb + (long)p * 4194304, 2097152L, 64L,
            Keb + (long)p * 524288, 262144L, 64L,
            SCu, 8388608L, 524288L, nullptr, nullptr,
            64, 1024, 1024, 256, 0.125f, 16, 1, MFMA_TAIL);
        softmax_gate_kernel<2><<<16384, 256, 0, stream>>>(
            SCu, GU + p * 4096, GM + p * 512, 15, 2047, 2048, 256);
        mfma_nt<64, 0, false><<<dim3(1, 16, 32), 256, 0, stream>>>(
            SCu, 8388608L, 524288L,
            VTe + (long)p * 524288, 262144L, 16384L,
            (void*)(CTe + (long)p * 4194304), 2097152L, 64L, nullptr, nullptr,
            256, 256, 256, 1024, 1.0f, 16, 1, MFMA_TAIL);
    }
    // 12. emer out-proj + residual + r_emer_scalar -> o_micro_new
    mfma_nt<128, 3, true><<<dim3(8, 64, 1), 256, 0, stream>>>(
        CTe, 0L, 0L, WB + 7 * 1048576, 0L, 0L, out_micro, 0L, 0L, nullptr, nullptr,
        1024, 1024, 1024, 1024, 1.0f, 1, 1, o_micro, RES, nullptr, nullptr, 0L, 0);
}

// Round 7
// 421.726 us; speedup vs baseline: 1.6674x; 1.0041x over previous
//
#include <hip/hip_runtime.h>
#include <math.h>

// B=4, TU=2048, TM=256, D=1024, H=16, DH=64, PAIRS=512
typedef unsigned short u16;
typedef __attribute__((ext_vector_type(8))) short bf16x8;
typedef __attribute__((ext_vector_type(4))) float f32x4;

__device__ __forceinline__ float sigmoidf_(float x) { return 1.0f / (1.0f + __expf(-x)); }
__device__ __forceinline__ u16 f2bf(float v) {
    union { float f; unsigned u; } x; x.f = v;
    unsigned r = x.u + 0x7fffu + ((x.u >> 16) & 1u);
    return (u16)(r >> 16);
}
__device__ __forceinline__ float bf2f(u16 u) {
    union { unsigned u; float f; } x; x.u = ((unsigned)u) << 16; return x.f;
}

// ---------------------------------------------------------------------------
// balance_norm + gate + fused pair(phase)-normalization.
// ---------------------------------------------------------------------------
__global__ void __launch_bounds__(256) norm_gate_kernel(
    const float* __restrict__ X,
    const float* __restrict__ w, const float* __restrict__ bvec,
    const float* __restrict__ bw_p,
    const float* __restrict__ gw, const float* __restrict__ gb_p,
    u16* __restrict__ OUT, u16* __restrict__ PN, float* __restrict__ G)
{
    const int row = blockIdx.x;
    const int t = threadIdx.x;
    const float* xr = X + (size_t)row * 1024;
    float4 x4 = *(const float4*)(xr + 4 * t);
    __shared__ float sh1[256], sh2[256];
    sh1[t] = x4.x + x4.y + x4.z + x4.w;
    sh2[t] = x4.x * x4.x + x4.y * x4.y + x4.z * x4.z + x4.w * x4.w;
    __syncthreads();
    for (int o = 64; o > 0; o >>= 1) {
        if ((t & 127) < o) sh2[t] += sh2[t + o];
        __syncthreads();
    }
    const float slo = sh2[0], shi = sh2[128];
    for (int o = 128; o > 0; o >>= 1) {
        if (t < o) sh1[t] += sh1[t + o];
        __syncthreads();
    }
    const float mu = sh1[0] * (1.0f / 1024.0f);
    const float var = (slo + shi) * (1.0f / 1024.0f) - mu * mu;
    const float rstd = rsqrtf(var + 1e-6f);
    const float imb = (slo - shi) * (1.0f / 512.0f) * (*bw_p);
    const float corr = (t < 128) ? -imb : imb;
    const int i0 = 4 * t;
    float o0 = (x4.x - mu) * rstd * w[i0 + 0] + bvec[i0 + 0] + corr;
    float o1 = (x4.y - mu) * rstd * w[i0 + 1] + bvec[i0 + 1] + corr;
    float o2 = (x4.z - mu) * rstd * w[i0 + 2] + bvec[i0 + 2] + corr;
    float o3 = (x4.w - mu) * rstd * w[i0 + 3] + bvec[i0 + 3] + corr;
    float gd = o0 * gw[i0 + 0] + o1 * gw[i0 + 1] + o2 * gw[i0 + 2] + o3 * gw[i0 + 3];
    __syncthreads();
    sh1[t] = gd;
    __syncthreads();
    for (int o = 128; o > 0; o >>= 1) {
        if (t < o) sh1[t] += sh1[t + o];
        __syncthreads();
    }
    if (t == 0) G[row] = sigmoidf_(sh1[0] + *gb_p);
    u16 ob[4] = { f2bf(o0), f2bf(o1), f2bf(o2), f2bf(o3) };
    *(uint2*)(OUT + (size_t)row * 1024 + i0) = *(uint2*)ob;
    float pa = o0 + 1e-8f, pb = o1 + 1e-8f;
    float r0 = rsqrtf(pa * pa + pb * pb);
    float pc = o2 + 1e-8f, pd = o3 + 1e-8f;
    float r1 = rsqrtf(pc * pc + pd * pd);
    u16 pn[4] = { f2bf(pa * r0), f2bf(pb * r0), f2bf(pc * r1), f2bf(pd * r1) };
    *(uint2*)(PN + (size_t)row * 1024 + i0) = *(uint2*)pn;
}

// ---------------------------------------------------------------------------
// weight fp32 -> bf16 (8 slots of 1M elements; order set by pointer args)
// ---------------------------------------------------------------------------
__global__ void __launch_bounds__(256) wconv_kernel(
    const float* w0, const float* w1, const float* w2, const float* w3,
    const float* w4, const float* w5, const float* w6, const float* w7,
    u16* __restrict__ dst)
{
    const float* s;
    switch (blockIdx.y) {
        case 0: s = w0; break; case 1: s = w1; break;
        case 2: s = w2; break; case 3: s = w3; break;
        case 4: s = w4; break; case 5: s = w5; break;
        case 6: s = w6; break; default: s = w7; break;
    }
    long i = (long)blockIdx.x * 1024 + threadIdx.x * 4;
    float4 v = *(const float4*)(s + i);
    u16 o[4] = { f2bf(v.x), f2bf(v.y), f2bf(v.z), f2bf(v.w) };
    *(uint2*)(dst + (long)blockIdx.y * 1048576 + i) = *(uint2*)o;
}

__global__ void __launch_bounds__(256) cvt_kernel(const float* __restrict__ S, u16* __restrict__ D)
{
    long i = ((long)blockIdx.x * 256 + threadIdx.x) * 4;
    float4 v = *(const float4*)(S + i);
    u16 o[4] = { f2bf(v.x), f2bf(v.y), f2bf(v.z), f2bf(v.w) };
    *(uint2*)(D + i) = *(uint2*)o;
}

// ---------------------------------------------------------------------------
// bf16 NT MFMA GEMM, 128xBN tile, BK=32, 256 threads (2x2 waves).
// 3-STAGE LDS PIPELINE, 2 TILES IN FLIGHT (T3/T4).
// LDS in MFMA-fragment order (m173): conflict-free ds_read_b128.
// SWZ (2D grids, gy%8==0, gx%4==0): two-level L2 blocking — each XCD owns
// gy/8 contiguous by rows; within the chunk, bx walks in supertiles of 4 so
// the concurrent working set (8 A-panels + ~8 B-panels ~= 4MB) fits L2;
// A persists across supertiles, each B panel is read ~once per XCD.
// EPI 6/7 VT sections: epilogue LDS transpose -> coalesced uint4 stores.
// EPI 0: bf16 store                 2: f32 atomicAdd
//     3: f32 base[idx]+acc*rs[m]    5: resonance blend + transposed write
//     6: micro fused 3-way (Kc | VTc transposed | Qe)
//     7: macro fused 3-way (Qc | Ke | VTe transposed)
// ---------------------------------------------------------------------------
template<int BN, int EPI, bool SWZ>
__global__ void __launch_bounds__(256) mfma_nt(
    const u16* __restrict__ A, long zAb, long zAh,
    const u16* __restrict__ B, long zBb, long zBh,
    void* __restrict__ C, long zCb, long zCh,
    void* __restrict__ Cx, void* __restrict__ Cy,
    int K, int lda, int ldb, int ldc, float alpha, int nH, int nsplit,
    const float* __restrict__ base, const float* __restrict__ rs,
    const float* __restrict__ accB, float* __restrict__ OT,
    long zOT, int ldt)
{
    constexpr int NR = BN / 32;
    constexpr int ABUF = 128 * 32;   // u16 per A stage
    constexpr int BBUF = BN * 32;    // u16 per B stage
    __shared__ __align__(16) u16 sh[3 * (ABUF + BBUF)];
    u16* const Ab0 = sh;
    u16* const Bb0 = sh + 3 * ABUF;
    int bx, by, bz;
    if constexpr (SWZ) {
        // two-level L2-blocked XCD swizzle (2D grid only)
        const int gx = gridDim.x, gy = gridDim.y;
        const int lin = blockIdx.x + gx * blockIdx.y;
        const int xcd = lin & 7, c = lin >> 3;
        const int LBY = gy >> 3;                 // by rows per XCD
        const int SPB = 4 * LBY;                 // blocks per supertile
        const int sc = c / SPB, r = c - sc * SPB;
        const int byl = r >> 2, bxl = r & 3;
        by = xcd * LBY + byl;
        bx = sc * 4 + bxl;
        bz = 0;
    } else {
        bx = blockIdx.x; by = blockIdx.y; bz = blockIdx.z;
    }
    const int t = threadIdx.x;
    const int lane = t & 63, w = t >> 6;
    const int wr = w >> 1, wc = w & 1;
    const int slab = bz / nsplit, ks = bz - slab * nsplit;
    const int b = slab / nH, h = slab - b * nH;
    const int kchunk = K / nsplit;
    const int kbeg = ks * kchunk, kend = kbeg + kchunk;
    const long m0 = (long)by * 128;
    const long n0 = (long)bx * BN;
    const int frow = lane & 15, fko = (lane >> 4) * 8;
    const u16* gaA = A + zAb * b + zAh * h + (m0 + 32 * w + frow) * lda + fko;
    const u16* gbB;
    if constexpr (BN == 128) gbB = B + zBb * b + zBh * h + (n0 + 32 * w + frow) * ldb + fko;
    else                     gbB = B + zBb * b + zBh * h + (n0 + 16 * w + frow) * ldb + fko;

#define GLD(src, dst) __builtin_amdgcn_global_load_lds( \
        (const __attribute__((address_space(1))) void*)(src), \
        (__attribute__((address_space(3))) void*)(dst), 16, 0, 0)

    auto stage = [&](int kk, int p) {
        u16* ap = Ab0 + p * ABUF;
        u16* bp = Bb0 + p * BBUF;
        GLD(gaA + kk, ap + 2 * w * 512);
        GLD(gaA + 16L * lda + kk, ap + (2 * w + 1) * 512);
        if constexpr (BN == 128) {
            GLD(gbB + kk, bp + 2 * w * 512);
            GLD(gbB + 16L * ldb + kk, bp + (2 * w + 1) * 512);
        } else {
            GLD(gbB + kk, bp + w * 512);
        }
    };

    const int nIter = (kend - kbeg) >> 5;
    f32x4 acc[4][NR] = {};
    stage(kbeg, 0);
    if (nIter > 1) stage(kbeg + 32, 1);
    int cur = 0;
    for (int i = 0; i < nIter; ++i) {
        if (i + 2 < nIter) {
            int p2 = cur + 2; if (p2 >= 3) p2 -= 3;
            stage(kbeg + (i + 2) * 32, p2);
            if constexpr (BN == 128) asm volatile("s_waitcnt vmcnt(8)" ::: "memory");
            else                     asm volatile("s_waitcnt vmcnt(6)" ::: "memory");
        } else if (i + 1 < nIter) {
            if constexpr (BN == 128) asm volatile("s_waitcnt vmcnt(4)" ::: "memory");
            else                     asm volatile("s_waitcnt vmcnt(3)" ::: "memory");
        } else {
            asm volatile("s_waitcnt vmcnt(0)" ::: "memory");
        }
        __builtin_amdgcn_sched_barrier(0);
        __builtin_amdgcn_s_barrier();        // tile i visible to all waves
        __builtin_amdgcn_sched_barrier(0);
        const u16* ap = Ab0 + cur * ABUF;
        const u16* bp = Bb0 + cur * BBUF;
        bf16x8 af[4], bfr[NR];
        #pragma unroll
        for (int m = 0; m < 4; ++m)
            af[m] = *(const bf16x8*)(ap + (wr * 4 + m) * 512 + lane * 8);
        #pragma unroll
        for (int n = 0; n < NR; ++n)
            bfr[n] = *(const bf16x8*)(bp + (wc * NR + n) * 512 + lane * 8);
        asm volatile("s_waitcnt lgkmcnt(0)" ::: "memory");
        __builtin_amdgcn_sched_barrier(0);
        __builtin_amdgcn_s_barrier();        // all reads done; buf may be re-staged
        #pragma unroll
        for (int m = 0; m < 4; ++m)
            #pragma unroll
            for (int n = 0; n < NR; ++n)
                acc[m][n] = __builtin_amdgcn_mfma_f32_16x16x32_bf16(af[m], bfr[n], acc[m][n], 0, 0, 0);
        cur = (cur == 2) ? 0 : cur + 1;
    }
#undef GLD
    const long Coff = zCb * b + zCh * h;
    const int l15 = lane & 15, l4 = lane >> 4;
    if constexpr (EPI == 6 || EPI == 7) {
        constexpr int VTSEC = (EPI == 6) ? 1 : 2;
        if ((int)(n0 >> 10) == VTSEC) {
            // transpose through LDS -> coalesced 16B stores along T
            __syncthreads();
            #pragma unroll
            for (int m = 0; m < 4; ++m)
                #pragma unroll
                for (int n = 0; n < NR; ++n)
                    #pragma unroll
                    for (int j = 0; j < 4; ++j)
                        sh[(wc * 64 + n * 16 + l15) * 136 + (wr * 64 + m * 16 + l4 * 4 + j)]
                            = f2bf(acc[m][n][j] * alpha);
            __syncthreads();
            constexpr int  LT   = (EPI == 6) ? 2048 : 256;
            constexpr int  L2T  = (EPI == 6) ? 11 : 8;
            constexpr long BSTR = (EPI == 6) ? 2097152L : 262144L;
            u16* dst = (EPI == 6) ? (u16*)Cx : (u16*)Cy;
            const long bb  = m0 >> L2T;
            const int  tt0 = (int)(m0 & (LT - 1));
            const long colb = n0 & 1023;
            #pragma unroll
            for (int it = 0; it < 8; ++it) {
                const int c = it * 16 + (t >> 4);
                const int r = (t & 15) * 8;
                uint4 v = *(const uint4*)&sh[c * 136 + r];
                *(uint4*)&dst[bb * BSTR + (colb + c) * LT + tt0 + r] = v;
            }
            return;
        }
    }
    #pragma unroll
    for (int m = 0; m < 4; ++m) {
        #pragma unroll
        for (int n = 0; n < NR; ++n) {
            #pragma unroll
            for (int j = 0; j < 4; ++j) {
                const long grow = m0 + wr * 64 + m * 16 + l4 * 4 + j;
                const long gcol = n0 + wc * (BN / 2) + n * 16 + l15;
                const float v = acc[m][n][j] * alpha;
                if constexpr (EPI == 0) {
                    ((u16*)C)[Coff + grow * ldc + gcol] = f2bf(v);
                } else if constexpr (EPI == 2) {
                    atomicAdd((float*)C + Coff + grow * ldc + gcol, v);
                } else if constexpr (EPI == 3) {
                    const long idx = grow * ldc + gcol;
                    ((float*)C)[idx] = base[idx] + v * rs[grow];
                } else if constexpr (EPI == 5) {
                    const long idx = Coff + grow * ldc + gcol;
                    ((float*)C)[idx] = 0.7f * base[idx] + 0.3f * v;
                    const long tidx = zOT * b + gcol * (long)ldt + grow;
                    OT[tidx] = 0.7f * accB[tidx] + 0.3f * v;
                } else if constexpr (EPI == 6) {
                    if (n0 < 1024) ((u16*)C)[grow * 1024 + gcol] = f2bf(v);          // K_conv
                    else           ((u16*)Cy)[grow * 1024 + (gcol - 2048)] = f2bf(v); // Q_emer
                } else {  // EPI == 7
                    if (n0 < 1024) ((u16*)C)[grow * 1024 + gcol] = f2bf(v);          // Q_conv
                    else           ((u16*)Cx)[grow * 1024 + (gcol - 1024)] = f2bf(v); // K_emer
                }
            }
        }
    }
}

// ---------------------------------------------------------------------------
// softmax + gate + renorm, IN PLACE on bf16 scores; one wave per row.
// ---------------------------------------------------------------------------
template<int NU2>
__global__ void __launch_bounds__(256) softmax_gate_kernel(
    u16* __restrict__ P,
    const float* __restrict__ AG, const float* __restrict__ EG,
    int bshift, int qmask, int qld, int egld)
{
    const int row = blockIdx.x * 4 + (threadIdx.x >> 6);
    const int lane = threadIdx.x & 63;
    const int bl = row >> bshift;
    unsigned* pr = (unsigned*)(P + (long)row * (NU2 * 128));
    const float* egr = EG + (long)bl * egld;
    float r0[NU2], r1[NU2];
    float m = -3.4e38f;
    #pragma unroll
    for (int u = 0; u < NU2; ++u) {
        unsigned v = pr[lane + 64 * u];
        r0[u] = bf2f((u16)(v & 0xffffu));
        r1[u] = bf2f((u16)(v >> 16));
        m = fmaxf(m, fmaxf(r0[u], r1[u]));
    }
    for (int o = 32; o > 0; o >>= 1) m = fmaxf(m, __shfl_xor(m, o));
    float l = 0.0f, se = 0.0f;
    #pragma unroll
    for (int u = 0; u < NU2; ++u) {
        float e0 = __expf(r0[u] - m), e1 = __expf(r1[u] - m);
        l += e0 + e1;
        float2 eg = *(const float2*)(egr + 2 * (lane + 64 * u));
        r0[u] = e0 * eg.x; r1[u] = e1 * eg.y;
        se += r0[u] + r1[u];
    }
    for (int o = 32; o > 0; o >>= 1) { l += __shfl_xor(l, o); se += __shfl_xor(se, o); }
    const float ag = AG[(long)bl * qld + (row & qmask)];
    const float f = ag / (ag * se + l * 1e-8f);
    #pragma unroll
    for (int u = 0; u < NU2; ++u) {
        unsigned vo = (unsigned)f2bf(r0[u] * f) | ((unsigned)f2bf(r1[u] * f) << 16);
        pr[lane + 64 * u] = vo;
    }
}

__global__ void __launch_bounds__(256) rowmean_sig_kernel(
    const float* __restrict__ X, int len, float invlen,
    const float* __restrict__ alpha_p, float* __restrict__ OUT)
{
    const int row = blockIdx.x * 4 + (threadIdx.x >> 6);
    const int lane = threadIdx.x & 63;
    const float* xr = X + (long)row * len;
    float s = 0.0f;
    for (int k = lane; k < len; k += 64) s += xr[k];
    for (int o = 32; o > 0; o >>= 1) s += __shfl_xor(s, o);
    if (lane == 0) OUT[row] = sigmoidf_((*alpha_p) * s * invlen);
}

#define MFMA_TAIL nullptr, nullptr, nullptr, nullptr, 0L, 0

extern "C" void kernel_launch(void* const* d_in, const int* in_sizes, int n_in,
                              void* d_out, int out_size, void* d_ws, size_t ws_size,
                              hipStream_t stream)
{
    (void)in_sizes; (void)n_in; (void)out_size; (void)ws_size;
    const float* o_micro    = (const float*)d_in[0];
    const float* o_macro    = (const float*)d_in[1];
    const float* r_conv_acc = (const float*)d_in[2];
    const float* r_emer_acc = (const float*)d_in[3];
    const float* ln_u_w = (const float*)d_in[4];
    const float* ln_u_b = (const float*)d_in[5];
    const float* bw_u   = (const float*)d_in[6];
    const float* ln_m_w = (const float*)d_in[7];
    const float* ln_m_b = (const float*)d_in[8];
    const float* bw_m   = (const float*)d_in[9];
    const float* gu_w   = (const float*)d_in[10];
    const float* gu_b   = (const float*)d_in[11];
    const float* gm_w   = (const float*)d_in[12];
    const float* gm_b   = (const float*)d_in[13];
    const float* wq_c   = (const float*)d_in[14];
    const float* wk_c   = (const float*)d_in[15];
    const float* wv_c   = (const float*)d_in[16];
    const float* wo_c   = (const float*)d_in[17];
    const float* wq_e   = (const float*)d_in[18];
    const float* wk_e   = (const float*)d_in[19];
    const float* wv_e   = (const float*)d_in[20];
    const float* wo_e   = (const float*)d_in[21];
    const float* res_alpha = (const float*)d_in[22];

    float* out = (float*)d_out;
    float* out_micro = out;              // (4,2048,1024)
    float* out_macro = out + 8388608;    // (4,256,1024)
    float* out_rconv = out + 9437184;    // (4,256,2048)
    float* out_remer = out + 11534336;   // (4,2048,256)

    // workspace (f32 slot offsets; bf16 buffers use 2 el/slot)
    float* ws = (float*)d_ws;
    u16* OUb = (u16*)ws;                       // 8388608 bf16 (normed micro)
    u16* OMb = (u16*)(ws + 4194304);           // 1048576 bf16 (normed macro)
    u16* WB  = (u16*)(ws + 4718592);           // 8 x 1048576 bf16 weights
                                               //   [wk_c wv_c wq_e | wq_c wk_e wv_e | wo_c wo_e]
    u16* Kcb = (u16*)(ws + 8912896);           // conv K (8192x1024) -> later CTe
    u16* VTc = (u16*)(ws + 13107200);          // conv V^T [b][h][64][2048]
    u16* Qeb = (u16*)(ws + 17301504);          // emer Q (8192x1024)
    u16* Qcb = (u16*)(ws + 21495808);          // conv Q (1024x1024) -> later CTb
    u16* Keb = (u16*)(ws + 22020096);          // emer K (1024x1024)
    u16* VTe = (u16*)(ws + 22544384);          // emer V^T [b][h][64][256]
    u16* PNu = (u16*)(ws + 23068672);          // pairnormed micro (8.4M bf16)
    float* CT = ws + 27262976;                 // conv ctx f32 (4x256x1024); early: PNm
    float* GU = ws + 28311552;                 // 8192
    float* GM = GU + 8192;                     // 1024
    float* RCS = GM + 1024;                    // 1024
    float* RES = RCS + 1024;                   // 8192
    u16* PNm = (u16*)CT;
    u16* CTb = Qcb;
    u16* CTe = Kcb;
    u16* SCu = (u16*)out_micro;                // 2-batch bf16 score/prob slab (16.8M els)

    // 1. weights -> bf16, reordered for fused projections
    wconv_kernel<<<dim3(1024, 8), 256, 0, stream>>>(wk_c, wv_c, wq_e, wq_c, wk_e, wv_e, wo_c, wo_e, WB);
    // 2. balance norms + gates + fused pairnorm
    norm_gate_kernel<<<8192, 256, 0, stream>>>(o_micro, ln_u_w, ln_u_b, bw_u, gu_w, gu_b, OUb, PNu, GU);
    norm_gate_kernel<<<1024, 256, 0, stream>>>(o_macro, ln_m_w, ln_m_b, bw_m, gm_w, gm_b, OMb, PNm, GM);
    // 3. resonance GEMM + 0.7/0.3 blend + transposed write
    mfma_nt<128, 5, false><<<dim3(16, 2, 4), 256, 0, stream>>>(
        PNm, 262144L, 0L, PNu, 2097152L, 0L, out_rconv, 524288L, 0L, nullptr, nullptr,
        1024, 1024, 1024, 2048, 1.0f / 512.0f, 1, 1,
        r_conv_acc, nullptr, r_emer_acc, out_remer, 524288L, 256);
    // 4. resonance scalars
    rowmean_sig_kernel<<<256, 256, 0, stream>>>(out_rconv, 2048, 1.0f / 2048.0f, res_alpha, RCS);
    rowmean_sig_kernel<<<2048, 256, 0, stream>>>(out_remer, 256, 1.0f / 256.0f, res_alpha, RES);
    // 5. fused micro-side projections: [K_conv | VT_conv | Q_emer]
    mfma_nt<128, 6, true><<<dim3(24, 64, 1), 256, 0, stream>>>(
        OUb, 0L, 0L, WB, 0L, 0L, Kcb, 0L, 0L, VTc, Qeb,
        1024, 1024, 1024, 1024, 1.0f, 1, 1, MFMA_TAIL);
    // 6. fused macro-side projections: [Q_conv | K_emer | VT_emer]
    mfma_nt<128, 7, true><<<dim3(24, 8, 1), 256, 0, stream>>>(
        OMb, 0L, 0L, WB + 3 * 1048576, 0L, 0L, Qcb, 0L, 0L, Keb, VTe,
        1024, 1024, 1024, 1024, 1.0f, 1, 1, MFMA_TAIL);
    // 7. conv ctx accumulator
    (void)hipMemsetAsync(CT, 0, 1048576 * sizeof(float), stream);
    // 8. conv attention, 2 batches per dispatch
    for (int p = 0; p < 2; ++p) {
        mfma_nt<128, 0, false><<<dim3(16, 2, 32), 256, 0, stream>>>(
            Qcb + (long)p * 524288, 262144L, 64L,
            Kcb + (long)p * 4194304, 2097152L, 64L,
            SCu, 8388608L, 524288L, nullptr, nullptr,
            64, 1024, 1024, 2048, 0.125f, 16, 1, MFMA_TAIL);
        softmax_gate_kernel<16><<<2048, 256, 0, stream>>>(
            SCu, GM + p * 512, GU + p * 4096, 12, 255, 256, 2048);
        mfma_nt<64, 2, false><<<dim3(1, 2, 256), 256, 0, stream>>>(
            SCu, 8388608L, 524288L,
            VTc + (long)p * 4194304, 2097152L, 131072L,
            (void*)(CT + (long)p * 524288), 262144L, 64L, nullptr, nullptr,
            2048, 2048, 2048, 1024, 1.0f, 16, 8, MFMA_TAIL);
    }
    // 9-10. conv out-proj + residual + r_conv_scalar -> o_macro_new
    cvt_kernel<<<1024, 256, 0, stream>>>(CT, CTb);
    mfma_nt<128, 3, false><<<dim3(8, 8, 1), 256, 0, stream>>>(
        CTb, 0L, 0L, WB + 6 * 1048576, 0L, 0L, out_macro, 0L, 0L, nullptr, nullptr,
        1024, 1024, 1024, 1024, 1.0f, 1, 1, o_macro, RCS, nullptr, nullptr, 0L, 0);
    // 11. emer attention, 2 batches per dispatch
    for (int p = 0; p < 2; ++p) {
        mfma_nt<128, 0, false><<<dim3(2, 16, 32), 256, 0, stream>>>(
            Qeb + (long)p * 4194304, 2097152L, 64L,
            Keb + (long)p * 524288, 262144L, 64L,
            SCu, 8388608L, 524288L, nullptr, nullptr,
            64, 1024, 1024, 256, 0.125f, 16, 1, MFMA_TAIL);
        softmax_gate_kernel<2><<<16384, 256, 0, stream>>>(
            SCu, GU + p * 4096, GM + p * 512, 15, 2047, 2048, 256);
        mfma_nt<64, 0, false><<<dim3(1, 16, 32), 256, 0, stream>>>(
            SCu, 8388608L, 524288L,
            VTe + (long)p * 524288, 262144L, 16384L,
            (void*)(CTe + (long)p * 4194304), 2097152L, 64L, nullptr, nullptr,
            256, 256, 256, 1024, 1.0f, 16, 1, MFMA_TAIL);
    }
    // 12. emer out-proj + residual + r_emer_scalar -> o_micro_new
    mfma_nt<128, 3, true><<<dim3(8, 64, 1), 256, 0, stream>>>(
        CTe, 0L, 0L, WB + 7 * 1048576, 0L, 0L, out_micro, 0L, 0L, nullptr, nullptr,
        1024, 1024, 1024, 1024, 1.0f, 1, 1, o_micro, RES, nullptr, nullptr, 0L, 0);
}

// Round 8
// 393.708 us; speedup vs baseline: 1.7860x; 1.0712x over previous
//
#include <hip/hip_runtime.h>
#include <math.h>

// B=4, TU=2048, TM=256, D=1024, H=16, DH=64, PAIRS=512
typedef unsigned short u16;
typedef __attribute__((ext_vector_type(8))) short bf16x8;
typedef __attribute__((ext_vector_type(4))) float f32x4;

__device__ __forceinline__ float sigmoidf_(float x) { return 1.0f / (1.0f + __expf(-x)); }
__device__ __forceinline__ u16 f2bf(float v) {
    union { float f; unsigned u; } x; x.f = v;
    unsigned r = x.u + 0x7fffu + ((x.u >> 16) & 1u);
    return (u16)(r >> 16);
}
__device__ __forceinline__ float bf2f(u16 u) {
    union { unsigned u; float f; } x; x.u = ((unsigned)u) << 16; return x.f;
}

#define GLD(src, dst) __builtin_amdgcn_global_load_lds( \
        (const __attribute__((address_space(1))) void*)(src), \
        (__attribute__((address_space(3))) void*)(dst), 16, 0, 0)

// ---------------------------------------------------------------------------
// balance_norm + gate + fused pair(phase)-normalization.
// ---------------------------------------------------------------------------
__global__ void __launch_bounds__(256) norm_gate_kernel(
    const float* __restrict__ X,
    const float* __restrict__ w, const float* __restrict__ bvec,
    const float* __restrict__ bw_p,
    const float* __restrict__ gw, const float* __restrict__ gb_p,
    u16* __restrict__ OUT, u16* __restrict__ PN, float* __restrict__ G)
{
    const int row = blockIdx.x;
    const int t = threadIdx.x;
    const float* xr = X + (size_t)row * 1024;
    float4 x4 = *(const float4*)(xr + 4 * t);
    __shared__ float sh1[256], sh2[256];
    sh1[t] = x4.x + x4.y + x4.z + x4.w;
    sh2[t] = x4.x * x4.x + x4.y * x4.y + x4.z * x4.z + x4.w * x4.w;
    __syncthreads();
    for (int o = 64; o > 0; o >>= 1) {
        if ((t & 127) < o) sh2[t] += sh2[t + o];
        __syncthreads();
    }
    const float slo = sh2[0], shi = sh2[128];
    for (int o = 128; o > 0; o >>= 1) {
        if (t < o) sh1[t] += sh1[t + o];
        __syncthreads();
    }
    const float mu = sh1[0] * (1.0f / 1024.0f);
    const float var = (slo + shi) * (1.0f / 1024.0f) - mu * mu;
    const float rstd = rsqrtf(var + 1e-6f);
    const float imb = (slo - shi) * (1.0f / 512.0f) * (*bw_p);
    const float corr = (t < 128) ? -imb : imb;
    const int i0 = 4 * t;
    float o0 = (x4.x - mu) * rstd * w[i0 + 0] + bvec[i0 + 0] + corr;
    float o1 = (x4.y - mu) * rstd * w[i0 + 1] + bvec[i0 + 1] + corr;
    float o2 = (x4.z - mu) * rstd * w[i0 + 2] + bvec[i0 + 2] + corr;
    float o3 = (x4.w - mu) * rstd * w[i0 + 3] + bvec[i0 + 3] + corr;
    float gd = o0 * gw[i0 + 0] + o1 * gw[i0 + 1] + o2 * gw[i0 + 2] + o3 * gw[i0 + 3];
    __syncthreads();
    sh1[t] = gd;
    __syncthreads();
    for (int o = 128; o > 0; o >>= 1) {
        if (t < o) sh1[t] += sh1[t + o];
        __syncthreads();
    }
    if (t == 0) G[row] = sigmoidf_(sh1[0] + *gb_p);
    u16 ob[4] = { f2bf(o0), f2bf(o1), f2bf(o2), f2bf(o3) };
    *(uint2*)(OUT + (size_t)row * 1024 + i0) = *(uint2*)ob;
    float pa = o0 + 1e-8f, pb = o1 + 1e-8f;
    float r0 = rsqrtf(pa * pa + pb * pb);
    float pc = o2 + 1e-8f, pd = o3 + 1e-8f;
    float r1 = rsqrtf(pc * pc + pd * pd);
    u16 pn[4] = { f2bf(pa * r0), f2bf(pb * r0), f2bf(pc * r1), f2bf(pd * r1) };
    *(uint2*)(PN + (size_t)row * 1024 + i0) = *(uint2*)pn;
}

// ---------------------------------------------------------------------------
// weight fp32 -> bf16 (8 slots of 1M elements; order set by pointer args)
// ---------------------------------------------------------------------------
__global__ void __launch_bounds__(256) wconv_kernel(
    const float* w0, const float* w1, const float* w2, const float* w3,
    const float* w4, const float* w5, const float* w6, const float* w7,
    u16* __restrict__ dst)
{
    const float* s;
    switch (blockIdx.y) {
        case 0: s = w0; break; case 1: s = w1; break;
        case 2: s = w2; break; case 3: s = w3; break;
        case 4: s = w4; break; case 5: s = w5; break;
        case 6: s = w6; break; default: s = w7; break;
    }
    long i = (long)blockIdx.x * 1024 + threadIdx.x * 4;
    float4 v = *(const float4*)(s + i);
    u16 o[4] = { f2bf(v.x), f2bf(v.y), f2bf(v.z), f2bf(v.w) };
    *(uint2*)(dst + (long)blockIdx.y * 1048576 + i) = *(uint2*)o;
}

__global__ void __launch_bounds__(256) cvt_kernel(const float* __restrict__ S, u16* __restrict__ D)
{
    long i = ((long)blockIdx.x * 256 + threadIdx.x) * 4;
    float4 v = *(const float4*)(S + i);
    u16 o[4] = { f2bf(v.x), f2bf(v.y), f2bf(v.z), f2bf(v.w) };
    *(uint2*)(D + i) = *(uint2*)o;
}

// ---------------------------------------------------------------------------
// mfma8: 256xBN-tile bf16 NT GEMM, BK=32, 512 threads = 8 waves (2M x 4N),
// per-wave output 128 x BN/4.  RING-3 LDS, counted-vmcnt schedule (T3+T4):
//   iter i: stage(i+2) -> ring[(i+2)%3]; 8+NR ds_read_b128 from ring[i%3];
//   lgkmcnt(0); setprio(1); 8*NR MFMA; setprio(0); vmcnt(LPS) (stage i+2
//   stays IN FLIGHT across the barrier); ONE s_barrier.
// LDS fragment-order subtiles (m173): conflict-free ds_read, linear GLD dest.
// Bijective XCD swizzle + per-XCD supertile walk (L2 blocking).
// EPI 3: f32 base[idx]+acc*rs[row]
// EPI 6: micro fused 3-way sections (Kc bf16 | VTc transposed uint2 | Qe bf16)
// ---------------------------------------------------------------------------
template<int BN, int EPI>
__global__ void __launch_bounds__(512, 1) mfma8(
    const u16* __restrict__ A, const u16* __restrict__ B,
    void* __restrict__ C, void* __restrict__ Cx, void* __restrict__ Cy,
    int K, int lda, int ldb,
    const float* __restrict__ base, const float* __restrict__ rs)
{
    constexpr int NR = BN / 64;                 // N-frags per wave
    constexpr int RSTRIDE = 8192 + BN * 32;     // u16 per ring slot (A 16KB + B)
    __shared__ __align__(16) u16 sh[3 * RSTRIDE];
    // bijective XCD swizzle + supertile: XCD x owns by in [x*gy/8, ...), walks bx slowly
    const int gx = gridDim.x, gy = gridDim.y;
    const int lin = blockIdx.x + gx * blockIdx.y;
    const int xcd = lin & 7, off = lin >> 3;
    const int lby = gy >> 3;
    const int by = xcd * lby + (off % lby);
    const int bx = off / lby;
    const int t = threadIdx.x;
    const int lane = t & 63, w = t >> 6;
    const int wm = w >> 2, wn = w & 3;
    const long m0 = (long)by * 256;
    const long n0 = (long)bx * BN;
    const int frow = lane & 15, fk = (lane >> 4) * 8;
    const u16* Ag0 = A + (m0 + w * 16 + frow) * lda + fk;   // row-group w
    const u16* Ag1 = Ag0 + 128L * lda;                      // row-group 8+w
    const u16* Bg0 = B + (n0 + w * 16 + frow) * ldb + fk;   // col-group w
    const u16* Bg1 = Bg0 + 128L * ldb;                      // col-group 8+w (BN=256)

    auto stage = [&](int i, int r) {
        const int k0 = i << 5;
        u16* d = sh + r * RSTRIDE;
        GLD(Ag0 + k0, d + w * 512);
        GLD(Ag1 + k0, d + (8 + w) * 512);
        GLD(Bg0 + k0, d + 8192 + w * 512);
        if constexpr (BN == 256) GLD(Bg1 + k0, d + 8192 + (8 + w) * 512);
    };

    const int nIter = K >> 5;
    f32x4 acc[8][NR] = {};
    stage(0, 0);
    stage(1, 1);
    if constexpr (BN == 256) asm volatile("s_waitcnt vmcnt(4)" ::: "memory");
    else                     asm volatile("s_waitcnt vmcnt(3)" ::: "memory");
    __builtin_amdgcn_sched_barrier(0);
    __builtin_amdgcn_s_barrier();
    int r = 0;
    for (int i = 0; i < nIter; ++i) {
        if (i + 2 < nIter) {
            int r2 = r + 2; if (r2 >= 3) r2 -= 3;
            stage(i + 2, r2);
        }
        const u16* ra = sh + r * RSTRIDE;
        bf16x8 af[8], bf[NR];
        #pragma unroll
        for (int mi = 0; mi < 8; ++mi)
            af[mi] = *(const bf16x8*)(ra + (wm * 8 + mi) * 512 + lane * 8);
        #pragma unroll
        for (int ni = 0; ni < NR; ++ni)
            bf[ni] = *(const bf16x8*)(ra + 8192 + (wn * NR + ni) * 512 + lane * 8);
        asm volatile("s_waitcnt lgkmcnt(0)" ::: "memory");
        __builtin_amdgcn_sched_barrier(0);
        __builtin_amdgcn_s_setprio(1);
        #pragma unroll
        for (int mi = 0; mi < 8; ++mi)
            #pragma unroll
            for (int ni = 0; ni < NR; ++ni)
                acc[mi][ni] = __builtin_amdgcn_mfma_f32_16x16x32_bf16(af[mi], bf[ni], acc[mi][ni], 0, 0, 0);
        __builtin_amdgcn_s_setprio(0);
        if (i + 1 < nIter) {
            if (i + 2 < nIter) {
                if constexpr (BN == 256) asm volatile("s_waitcnt vmcnt(4)" ::: "memory");
                else                     asm volatile("s_waitcnt vmcnt(3)" ::: "memory");
            } else {
                asm volatile("s_waitcnt vmcnt(0)" ::: "memory");
            }
            __builtin_amdgcn_sched_barrier(0);
            __builtin_amdgcn_s_barrier();
        }
        ++r; if (r >= 3) r = 0;
    }
    // ---- epilogue ----
    const int l15 = lane & 15, l4 = lane >> 4;
    #pragma unroll
    for (int mi = 0; mi < 8; ++mi) {
        #pragma unroll
        for (int ni = 0; ni < NR; ++ni) {
            const long grow0 = m0 + wm * 128 + mi * 16 + l4 * 4;
            const long gcol  = n0 + wn * (BN / 4) + ni * 16 + l15;
            if constexpr (EPI == 3) {
                #pragma unroll
                for (int j = 0; j < 4; ++j) {
                    const long idx = (grow0 + j) * 1024 + gcol;
                    ((float*)C)[idx] = base[idx] + acc[mi][ni][j] * rs[grow0 + j];
                }
            } else {  // EPI == 6
                const int sec = (int)(n0 >> 10);
                if (sec == 0) {
                    #pragma unroll
                    for (int j = 0; j < 4; ++j)
                        ((u16*)C)[(grow0 + j) * 1024 + gcol] = f2bf(acc[mi][ni][j]);   // K_conv
                } else if (sec == 1) {
                    // VT_conv [b][h*64+d][2048 t]: 4 consecutive t -> one uint2
                    const long col = gcol - 1024;
                    u16 pk[4] = { f2bf(acc[mi][ni][0]), f2bf(acc[mi][ni][1]),
                                  f2bf(acc[mi][ni][2]), f2bf(acc[mi][ni][3]) };
                    const long idx = (grow0 >> 11) * 2097152 + col * 2048 + (grow0 & 2047);
                    *(uint2*)&((u16*)Cx)[idx] = *(uint2*)pk;
                } else {
                    #pragma unroll
                    for (int j = 0; j < 4; ++j)
                        ((u16*)Cy)[(grow0 + j) * 1024 + (gcol - 2048)] = f2bf(acc[mi][ni][j]); // Q_emer
                }
            }
        }
    }
}

// ---------------------------------------------------------------------------
// bf16 NT MFMA GEMM, 128xBN tile, BK=32, 256 threads (2x2 waves).
// 3-STAGE LDS PIPELINE, 2 TILES IN FLIGHT. (unchanged from round 7)
// ---------------------------------------------------------------------------
template<int BN, int EPI, bool SWZ>
__global__ void __launch_bounds__(256) mfma_nt(
    const u16* __restrict__ A, long zAb, long zAh,
    const u16* __restrict__ B, long zBb, long zBh,
    void* __restrict__ C, long zCb, long zCh,
    void* __restrict__ Cx, void* __restrict__ Cy,
    int K, int lda, int ldb, int ldc, float alpha, int nH, int nsplit,
    const float* __restrict__ base, const float* __restrict__ rs,
    const float* __restrict__ accB, float* __restrict__ OT,
    long zOT, int ldt)
{
    constexpr int NR = BN / 32;
    constexpr int ABUF = 128 * 32;
    constexpr int BBUF = BN * 32;
    __shared__ __align__(16) u16 sh[3 * (ABUF + BBUF)];
    u16* const Ab0 = sh;
    u16* const Bb0 = sh + 3 * ABUF;
    int bx, by, bz;
    if constexpr (SWZ) {
        const int gx = gridDim.x, gy = gridDim.y;
        const int lin = blockIdx.x + gx * blockIdx.y;
        const int xcd = lin & 7, c = lin >> 3;
        const int LBY = gy >> 3;
        const int SPB = 4 * LBY;
        const int sc = c / SPB, rr = c - sc * SPB;
        const int byl = rr >> 2, bxl = rr & 3;
        by = xcd * LBY + byl;
        bx = sc * 4 + bxl;
        bz = 0;
    } else {
        bx = blockIdx.x; by = blockIdx.y; bz = blockIdx.z;
    }
    const int t = threadIdx.x;
    const int lane = t & 63, w = t >> 6;
    const int wr = w >> 1, wc = w & 1;
    const int slab = bz / nsplit, ks = bz - slab * nsplit;
    const int b = slab / nH, h = slab - b * nH;
    const int kchunk = K / nsplit;
    const int kbeg = ks * kchunk, kend = kbeg + kchunk;
    const long m0 = (long)by * 128;
    const long n0 = (long)bx * BN;
    const int frow = lane & 15, fko = (lane >> 4) * 8;
    const u16* gaA = A + zAb * b + zAh * h + (m0 + 32 * w + frow) * lda + fko;
    const u16* gbB;
    if constexpr (BN == 128) gbB = B + zBb * b + zBh * h + (n0 + 32 * w + frow) * ldb + fko;
    else                     gbB = B + zBb * b + zBh * h + (n0 + 16 * w + frow) * ldb + fko;

    auto stage = [&](int kk, int p) {
        u16* ap = Ab0 + p * ABUF;
        u16* bp = Bb0 + p * BBUF;
        GLD(gaA + kk, ap + 2 * w * 512);
        GLD(gaA + 16L * lda + kk, ap + (2 * w + 1) * 512);
        if constexpr (BN == 128) {
            GLD(gbB + kk, bp + 2 * w * 512);
            GLD(gbB + 16L * ldb + kk, bp + (2 * w + 1) * 512);
        } else {
            GLD(gbB + kk, bp + w * 512);
        }
    };

    const int nIter = (kend - kbeg) >> 5;
    f32x4 acc[4][NR] = {};
    stage(kbeg, 0);
    if (nIter > 1) stage(kbeg + 32, 1);
    int cur = 0;
    for (int i = 0; i < nIter; ++i) {
        if (i + 2 < nIter) {
            int p2 = cur + 2; if (p2 >= 3) p2 -= 3;
            stage(kbeg + (i + 2) * 32, p2);
            if constexpr (BN == 128) asm volatile("s_waitcnt vmcnt(8)" ::: "memory");
            else                     asm volatile("s_waitcnt vmcnt(6)" ::: "memory");
        } else if (i + 1 < nIter) {
            if constexpr (BN == 128) asm volatile("s_waitcnt vmcnt(4)" ::: "memory");
            else                     asm volatile("s_waitcnt vmcnt(3)" ::: "memory");
        } else {
            asm volatile("s_waitcnt vmcnt(0)" ::: "memory");
        }
        __builtin_amdgcn_sched_barrier(0);
        __builtin_amdgcn_s_barrier();
        __builtin_amdgcn_sched_barrier(0);
        const u16* ap = Ab0 + cur * ABUF;
        const u16* bp = Bb0 + cur * BBUF;
        bf16x8 af[4], bfr[NR];
        #pragma unroll
        for (int m = 0; m < 4; ++m)
            af[m] = *(const bf16x8*)(ap + (wr * 4 + m) * 512 + lane * 8);
        #pragma unroll
        for (int n = 0; n < NR; ++n)
            bfr[n] = *(const bf16x8*)(bp + (wc * NR + n) * 512 + lane * 8);
        asm volatile("s_waitcnt lgkmcnt(0)" ::: "memory");
        __builtin_amdgcn_sched_barrier(0);
        __builtin_amdgcn_s_barrier();
        #pragma unroll
        for (int m = 0; m < 4; ++m)
            #pragma unroll
            for (int n = 0; n < NR; ++n)
                acc[m][n] = __builtin_amdgcn_mfma_f32_16x16x32_bf16(af[m], bfr[n], acc[m][n], 0, 0, 0);
        cur = (cur == 2) ? 0 : cur + 1;
    }
    const long Coff = zCb * b + zCh * h;
    const int l15 = lane & 15, l4 = lane >> 4;
    if constexpr (EPI == 6 || EPI == 7) {
        constexpr int VTSEC = (EPI == 6) ? 1 : 2;
        if ((int)(n0 >> 10) == VTSEC) {
            __syncthreads();
            #pragma unroll
            for (int m = 0; m < 4; ++m)
                #pragma unroll
                for (int n = 0; n < NR; ++n)
                    #pragma unroll
                    for (int j = 0; j < 4; ++j)
                        sh[(wc * 64 + n * 16 + l15) * 136 + (wr * 64 + m * 16 + l4 * 4 + j)]
                            = f2bf(acc[m][n][j] * alpha);
            __syncthreads();
            constexpr int  LT   = (EPI == 6) ? 2048 : 256;
            constexpr int  L2T  = (EPI == 6) ? 11 : 8;
            constexpr long BSTR = (EPI == 6) ? 2097152L : 262144L;
            u16* dst = (EPI == 6) ? (u16*)Cx : (u16*)Cy;
            const long bb  = m0 >> L2T;
            const int  tt0 = (int)(m0 & (LT - 1));
            const long colb = n0 & 1023;
            #pragma unroll
            for (int it = 0; it < 8; ++it) {
                const int c = it * 16 + (t >> 4);
                const int rr = (t & 15) * 8;
                uint4 v = *(const uint4*)&sh[c * 136 + rr];
                *(uint4*)&dst[bb * BSTR + (colb + c) * LT + tt0 + rr] = v;
            }
            return;
        }
    }
    #pragma unroll
    for (int m = 0; m < 4; ++m) {
        #pragma unroll
        for (int n = 0; n < NR; ++n) {
            #pragma unroll
            for (int j = 0; j < 4; ++j) {
                const long grow = m0 + wr * 64 + m * 16 + l4 * 4 + j;
                const long gcol = n0 + wc * (BN / 2) + n * 16 + l15;
                const float v = acc[m][n][j] * alpha;
                if constexpr (EPI == 0) {
                    ((u16*)C)[Coff + grow * ldc + gcol] = f2bf(v);
                } else if constexpr (EPI == 2) {
                    atomicAdd((float*)C + Coff + grow * ldc + gcol, v);
                } else if constexpr (EPI == 3) {
                    const long idx = grow * ldc + gcol;
                    ((float*)C)[idx] = base[idx] + v * rs[grow];
                } else if constexpr (EPI == 5) {
                    const long idx = Coff + grow * ldc + gcol;
                    ((float*)C)[idx] = 0.7f * base[idx] + 0.3f * v;
                    const long tidx = zOT * b + gcol * (long)ldt + grow;
                    OT[tidx] = 0.7f * accB[tidx] + 0.3f * v;
                } else if constexpr (EPI == 6) {
                    if (n0 < 1024) ((u16*)C)[grow * 1024 + gcol] = f2bf(v);
                    else           ((u16*)Cy)[grow * 1024 + (gcol - 2048)] = f2bf(v);
                } else {  // EPI == 7
                    if (n0 < 1024) ((u16*)C)[grow * 1024 + gcol] = f2bf(v);
                    else           ((u16*)Cx)[grow * 1024 + (gcol - 1024)] = f2bf(v);
                }
            }
        }
    }
}

// ---------------------------------------------------------------------------
// softmax + gate + renorm, IN PLACE on bf16 scores; one wave per row.
// ---------------------------------------------------------------------------
template<int NU2>
__global__ void __launch_bounds__(256) softmax_gate_kernel(
    u16* __restrict__ P,
    const float* __restrict__ AG, const float* __restrict__ EG,
    int bshift, int qmask, int qld, int egld)
{
    const int row = blockIdx.x * 4 + (threadIdx.x >> 6);
    const int lane = threadIdx.x & 63;
    const int bl = row >> bshift;
    unsigned* pr = (unsigned*)(P + (long)row * (NU2 * 128));
    const float* egr = EG + (long)bl * egld;
    float r0[NU2], r1[NU2];
    float m = -3.4e38f;
    #pragma unroll
    for (int u = 0; u < NU2; ++u) {
        unsigned v = pr[lane + 64 * u];
        r0[u] = bf2f((u16)(v & 0xffffu));
        r1[u] = bf2f((u16)(v >> 16));
        m = fmaxf(m, fmaxf(r0[u], r1[u]));
    }
    for (int o = 32; o > 0; o >>= 1) m = fmaxf(m, __shfl_xor(m, o));
    float l = 0.0f, se = 0.0f;
    #pragma unroll
    for (int u = 0; u < NU2; ++u) {
        float e0 = __expf(r0[u] - m), e1 = __expf(r1[u] - m);
        l += e0 + e1;
        float2 eg = *(const float2*)(egr + 2 * (lane + 64 * u));
        r0[u] = e0 * eg.x; r1[u] = e1 * eg.y;
        se += r0[u] + r1[u];
    }
    for (int o = 32; o > 0; o >>= 1) { l += __shfl_xor(l, o); se += __shfl_xor(se, o); }
    const float ag = AG[(long)bl * qld + (row & qmask)];
    const float f = ag / (ag * se + l * 1e-8f);
    #pragma unroll
    for (int u = 0; u < NU2; ++u) {
        unsigned vo = (unsigned)f2bf(r0[u] * f) | ((unsigned)f2bf(r1[u] * f) << 16);
        pr[lane + 64 * u] = vo;
    }
}

__global__ void __launch_bounds__(256) rowmean_sig_kernel(
    const float* __restrict__ X, int len, float invlen,
    const float* __restrict__ alpha_p, float* __restrict__ OUT)
{
    const int row = blockIdx.x * 4 + (threadIdx.x >> 6);
    const int lane = threadIdx.x & 63;
    const float* xr = X + (long)row * len;
    float s = 0.0f;
    for (int k = lane; k < len; k += 64) s += xr[k];
    for (int o = 32; o > 0; o >>= 1) s += __shfl_xor(s, o);
    if (lane == 0) OUT[row] = sigmoidf_((*alpha_p) * s * invlen);
}

#define MFMA_TAIL nullptr, nullptr, nullptr, nullptr, 0L, 0

extern "C" void kernel_launch(void* const* d_in, const int* in_sizes, int n_in,
                              void* d_out, int out_size, void* d_ws, size_t ws_size,
                              hipStream_t stream)
{
    (void)in_sizes; (void)n_in; (void)out_size; (void)ws_size;
    const float* o_micro    = (const float*)d_in[0];
    const float* o_macro    = (const float*)d_in[1];
    const float* r_conv_acc = (const float*)d_in[2];
    const float* r_emer_acc = (const float*)d_in[3];
    const float* ln_u_w = (const float*)d_in[4];
    const float* ln_u_b = (const float*)d_in[5];
    const float* bw_u   = (const float*)d_in[6];
    const float* ln_m_w = (const float*)d_in[7];
    const float* ln_m_b = (const float*)d_in[8];
    const float* bw_m   = (const float*)d_in[9];
    const float* gu_w   = (const float*)d_in[10];
    const float* gu_b   = (const float*)d_in[11];
    const float* gm_w   = (const float*)d_in[12];
    const float* gm_b   = (const float*)d_in[13];
    const float* wq_c   = (const float*)d_in[14];
    const float* wk_c   = (const float*)d_in[15];
    const float* wv_c   = (const float*)d_in[16];
    const float* wo_c   = (const float*)d_in[17];
    const float* wq_e   = (const float*)d_in[18];
    const float* wk_e   = (const float*)d_in[19];
    const float* wv_e   = (const float*)d_in[20];
    const float* wo_e   = (const float*)d_in[21];
    const float* res_alpha = (const float*)d_in[22];

    float* out = (float*)d_out;
    float* out_micro = out;              // (4,2048,1024)
    float* out_macro = out + 8388608;    // (4,256,1024)
    float* out_rconv = out + 9437184;    // (4,256,2048)
    float* out_remer = out + 11534336;   // (4,2048,256)

    // workspace (f32 slot offsets; bf16 buffers use 2 el/slot)
    float* ws = (float*)d_ws;
    u16* OUb = (u16*)ws;                       // 8388608 bf16 (normed micro)
    u16* OMb = (u16*)(ws + 4194304);           // 1048576 bf16 (normed macro)
    u16* WB  = (u16*)(ws + 4718592);           // 8 x 1048576 bf16 weights
                                               //   [wk_c wv_c wq_e | wq_c wk_e wv_e | wo_c wo_e]
    u16* Kcb = (u16*)(ws + 8912896);           // conv K (8192x1024) -> later CTe
    u16* VTc = (u16*)(ws + 13107200);          // conv V^T [b][h][64][2048]
    u16* Qeb = (u16*)(ws + 17301504);          // emer Q (8192x1024)
    u16* Qcb = (u16*)(ws + 21495808);          // conv Q (1024x1024) -> later CTb
    u16* Keb = (u16*)(ws + 22020096);          // emer K (1024x1024)
    u16* VTe = (u16*)(ws + 22544384);          // emer V^T [b][h][64][256]
    u16* PNu = (u16*)(ws + 23068672);          // pairnormed micro (8.4M bf16)
    float* CT = ws + 27262976;                 // conv ctx f32 (4x256x1024); early: PNm
    float* GU = ws + 28311552;                 // 8192
    float* GM = GU + 8192;                     // 1024
    float* RCS = GM + 1024;                    // 1024
    float* RES = RCS + 1024;                   // 8192
    u16* PNm = (u16*)CT;
    u16* CTb = Qcb;
    u16* CTe = Kcb;
    u16* SCu = (u16*)out_micro;                // 2-batch bf16 score/prob slab (16.8M els)

    // 1. weights -> bf16, reordered for fused projections
    wconv_kernel<<<dim3(1024, 8), 256, 0, stream>>>(wk_c, wv_c, wq_e, wq_c, wk_e, wv_e, wo_c, wo_e, WB);
    // 2. balance norms + gates + fused pairnorm
    norm_gate_kernel<<<8192, 256, 0, stream>>>(o_micro, ln_u_w, ln_u_b, bw_u, gu_w, gu_b, OUb, PNu, GU);
    norm_gate_kernel<<<1024, 256, 0, stream>>>(o_macro, ln_m_w, ln_m_b, bw_m, gm_w, gm_b, OMb, PNm, GM);
    // 3. resonance GEMM + 0.7/0.3 blend + transposed write
    mfma_nt<128, 5, false><<<dim3(16, 2, 4), 256, 0, stream>>>(
        PNm, 262144L, 0L, PNu, 2097152L, 0L, out_rconv, 524288L, 0L, nullptr, nullptr,
        1024, 1024, 1024, 2048, 1.0f / 512.0f, 1, 1,
        r_conv_acc, nullptr, r_emer_acc, out_remer, 524288L, 256);
    // 4. resonance scalars
    rowmean_sig_kernel<<<256, 256, 0, stream>>>(out_rconv, 2048, 1.0f / 2048.0f, res_alpha, RCS);
    rowmean_sig_kernel<<<2048, 256, 0, stream>>>(out_remer, 256, 1.0f / 256.0f, res_alpha, RES);
    // 5. fused micro-side projections: [K_conv | VT_conv | Q_emer]  (mfma8, 256x256)
    mfma8<256, 6><<<dim3(12, 32), 512, 0, stream>>>(
        OUb, WB, Kcb, VTc, Qeb, 1024, 1024, 1024, nullptr, nullptr);
    // 6. fused macro-side projections: [Q_conv | K_emer | VT_emer]
    mfma_nt<128, 7, true><<<dim3(24, 8, 1), 256, 0, stream>>>(
        OMb, 0L, 0L, WB + 3 * 1048576, 0L, 0L, Qcb, 0L, 0L, Keb, VTe,
        1024, 1024, 1024, 1024, 1.0f, 1, 1, MFMA_TAIL);
    // 7. conv ctx accumulator
    (void)hipMemsetAsync(CT, 0, 1048576 * sizeof(float), stream);
    // 8. conv attention, 2 batches per dispatch
    for (int p = 0; p < 2; ++p) {
        mfma_nt<128, 0, false><<<dim3(16, 2, 32), 256, 0, stream>>>(
            Qcb + (long)p * 524288, 262144L, 64L,
            Kcb + (long)p * 4194304, 2097152L, 64L,
            SCu, 8388608L, 524288L, nullptr, nullptr,
            64, 1024, 1024, 2048, 0.125f, 16, 1, MFMA_TAIL);
        softmax_gate_kernel<16><<<2048, 256, 0, stream>>>(
            SCu, GM + p * 512, GU + p * 4096, 12, 255, 256, 2048);
        mfma_nt<64, 2, false><<<dim3(1, 2, 256), 256, 0, stream>>>(
            SCu, 8388608L, 524288L,
            VTc + (long)p * 4194304, 2097152L, 131072L,
            (void*)(CT + (long)p * 524288), 262144L, 64L, nullptr, nullptr,
            2048, 2048, 2048, 1024, 1.0f, 16, 8, MFMA_TAIL);
    }
    // 9-10. conv out-proj + residual + r_conv_scalar -> o_macro_new
    cvt_kernel<<<1024, 256, 0, stream>>>(CT, CTb);
    mfma_nt<128, 3, false><<<dim3(8, 8, 1), 256, 0, stream>>>(
        CTb, 0L, 0L, WB + 6 * 1048576, 0L, 0L, out_macro, 0L, 0L, nullptr, nullptr,
        1024, 1024, 1024, 1024, 1.0f, 1, 1, o_macro, RCS, nullptr, nullptr, 0L, 0);
    // 11. emer attention, 2 batches per dispatch
    for (int p = 0; p < 2; ++p) {
        mfma_nt<128, 0, false><<<dim3(2, 16, 32), 256, 0, stream>>>(
            Qeb + (long)p * 4194304, 2097152L, 64L,
            Keb + (long)p * 524288, 262144L, 64L,
            SCu, 8388608L, 524288L, nullptr, nullptr,
            64, 1024, 1024, 256, 0.125f, 16, 1, MFMA_TAIL);
        softmax_gate_kernel<2><<<16384, 256, 0, stream>>>(
            SCu, GU + p * 4096, GM + p * 512, 15, 2047, 2048, 256);
        mfma_nt<64, 0, false><<<dim3(1, 16, 32), 256, 0, stream>>>(
            SCu, 8388608L, 524288L,
            VTe + (long)p * 524288, 262144L, 16384L,
            (void*)(CTe + (long)p * 4194304), 2097152L, 64L, nullptr, nullptr,
            256, 256, 256, 1024, 1.0f, 16, 1, MFMA_TAIL);
    }
    // 12. emer out-proj + residual + r_emer_scalar -> o_micro_new  (mfma8, 256x128)
    mfma8<128, 3><<<dim3(8, 32), 512, 0, stream>>>(
        CTe, WB + 7 * 1048576, out_micro, nullptr, nullptr,
        1024, 1024, 1024, o_micro, RES);
}